// Round 14
// baseline (99.926 us; speedup 1.0000x reference)
//
#include <hip/hip_runtime.h>

#define DM 1024
#define NH 16
#define DK 64
#define SEQ 2048

typedef __attribute__((ext_vector_type(8))) __bf16 bf16x8;
typedef __attribute__((ext_vector_type(4))) float f32x4;
typedef __attribute__((ext_vector_type(16))) float f32x16;
typedef __attribute__((ext_vector_type(8))) unsigned short u16x8;
typedef __attribute__((ext_vector_type(4))) unsigned int u32x4;
typedef unsigned short u16;

#define MFMA(a, b, c) __builtin_amdgcn_mfma_f32_16x16x32_bf16(a, b, c, 0, 0, 0)
#define MFMA32(a, b, c) __builtin_amdgcn_mfma_f32_32x32x16_bf16(a, b, c, 0, 0, 0)

__device__ __forceinline__ u16 f2bf(float f) {
    unsigned u = __builtin_bit_cast(unsigned, f);
    u = (u + 0x7FFFu + ((u >> 16) & 1u)) >> 16;
    return (u16)u;
}

__device__ __forceinline__ bf16x8 ldb(const u16* p) {
    u16x8 v = *(const u16x8*)p;
    return __builtin_bit_cast(bf16x8, v);
}

__device__ __forceinline__ unsigned cvtpk(float a, float b) {
    unsigned r;
    asm("v_cvt_pk_bf16_f32 %0, %1, %2" : "=v"(r) : "v"(a), "v"(b));
    return r;
}

__device__ __forceinline__ void swap32(unsigned& a, unsigned& b) {
    asm volatile("v_permlane32_swap_b32 %0, %1" : "+v"(a), "+v"(b));
}

__device__ __forceinline__ float fexp2(float x) {
    return __builtin_amdgcn_exp2f(x);
}

// async global->LDS, 16B per lane, LDS dest = wave-uniform base + lane*16
__device__ __forceinline__ void gload16(const u16* g, u16* l) {
    __builtin_amdgcn_global_load_lds(
        (const __attribute__((address_space(1))) unsigned int*)g,
        (__attribute__((address_space(3))) unsigned int*)l, 16, 0, 0);
}

// ================= fused prep: cvt + trig table + 4 weight transposes =================
#define NB_CVT 4096
#define NB_TRIG 256
#define NB_TQ 1024
#define NB_TK 64
#define NB_TV 64
#define NB_TO 1024

__device__ __forceinline__ void do_transpose(const float* __restrict__ W,
                                             u16* __restrict__ WT, int ldW, int K,
                                             int bx, int by, float (*t)[33]) {
    int n0 = bx * 32, k0 = by * 32;
    int tx = threadIdx.x & 31, ty = threadIdx.x >> 5;
#pragma unroll
    for (int i = 0; i < 32; i += 8)
        t[ty + i][tx] = W[(long)(k0 + ty + i) * ldW + n0 + tx];
    __syncthreads();
#pragma unroll
    for (int i = 0; i < 32; i += 8)
        WT[(long)(n0 + ty + i) * K + k0 + tx] = f2bf(t[tx][ty + i]);
}

__global__ __launch_bounds__(256) void k_prep(const float* __restrict__ x,
                                              u16* __restrict__ xb,
                                              float2* __restrict__ tab,
                                              const float* __restrict__ Wq,
                                              const float* __restrict__ Wk,
                                              const float* __restrict__ Wv,
                                              u16* __restrict__ WqkvT,
                                              const float* __restrict__ Wo,
                                              u16* __restrict__ WobT) {
    __shared__ float tsh[32][33];
    int blk = blockIdx.x;
    if (blk < NB_CVT) {  // f32 -> bf16 convert, x4 vectorized
        int i = blk * 256 + threadIdx.x;
        float4 v = ((const float4*)x)[i];
        ushort4 o;
        o.x = f2bf(v.x); o.y = f2bf(v.y); o.z = f2bf(v.z); o.w = f2bf(v.w);
        ((ushort4*)xb)[i] = o;
        return;
    }
    blk -= NB_CVT;
    if (blk < NB_TRIG) {  // sincos table tab[s][i]
        int idx = blk * 256 + threadIdx.x;
        int i = idx & 31, s = idx >> 5;
        float theta = exp2f(-(float)i * 0.4152410118609203f);  // 10000^(-2i/64)
        float sn, cs;
        sincosf((float)s * theta, &sn, &cs);
        tab[idx] = make_float2(cs, sn);
        return;
    }
    blk -= NB_TRIG;
    if (blk < NB_TQ) { do_transpose(Wq, WqkvT, DM, DM, blk & 31, blk >> 5, tsh); return; }
    blk -= NB_TQ;
    if (blk < NB_TK) { do_transpose(Wk, WqkvT + (size_t)DM * DM, DK, DM, blk & 1, blk >> 1, tsh); return; }
    blk -= NB_TK;
    if (blk < NB_TV) { do_transpose(Wv, WqkvT + (size_t)(DM + DK) * DM, DK, DM, blk & 1, blk >> 1, tsh); return; }
    blk -= NB_TV;
    do_transpose(Wo, WobT, DM, DM, blk & 31, blk >> 5, tsh);
}

// ========== ring-2 GEMM, counted vmcnt: C[M][N'] = A[M][K=1024] * BT[N'][K]^T ==========
template <int MODE>
__global__ __launch_bounds__(256) void k_gemm_r2(const u16* __restrict__ A,
                                                 const u16* __restrict__ BT,
                                                 void* __restrict__ out0,
                                                 void* __restrict__ out1,
                                                 void* __restrict__ out2,
                                                 const float2* __restrict__ tab) {
    extern __shared__ __align__(16) u16 lds[];  // [2][A:8192] ++ [2][B:8192]
    const int NT = 16;                          // K=1024 / 64
    const int K = DM;
    int tid = threadIdx.x;
    int w = tid >> 6, lane = tid & 63, lg = lane >> 4, lr = lane & 15;
    int wr = w >> 1, wc = w & 1;
    long m0 = (long)blockIdx.y * 128, n0 = (long)blockIdx.x * 128;
    int lrow = lane >> 3, lcol = (lane & 7) * 8;

    f32x4 acc[4][4] = {};

#define GSTAGE(t)                                                                   \
    {                                                                               \
        u16* as_ = lds + ((t) & 1) * 8192;                                          \
        u16* bs_ = lds + 16384 + ((t) & 1) * 8192;                                  \
        int k0_ = (t) * 64;                                                         \
        _Pragma("unroll") for (int it = 0; it < 4; ++it) {                          \
            int row = w * 32 + it * 8;                                              \
            gload16(A + (m0 + row + lrow) * K + k0_ + lcol, as_ + row * 64);        \
            gload16(BT + (n0 + row + lrow) * K + k0_ + lcol, bs_ + row * 64);       \
        }                                                                           \
    }

    GSTAGE(0);
    GSTAGE(1);
    for (int t = 0; t < NT; ++t) {
        if (t + 1 < NT) {
            asm volatile("s_waitcnt vmcnt(8)" ::: "memory");  // K-step t landed (mine)
        } else {
            asm volatile("s_waitcnt vmcnt(0)" ::: "memory");
        }
        __builtin_amdgcn_s_barrier();  // K-step t landed (all waves)
        const u16* as = lds + (t & 1) * 8192;
        const u16* bs = lds + 16384 + (t & 1) * 8192;
#pragma unroll
        for (int kk = 0; kk < 64; kk += 32) {
            bf16x8 af[4], bf[4];
#pragma unroll
            for (int i = 0; i < 4; ++i) {
                af[i] = ldb(as + (wr * 64 + i * 16 + lr) * 64 + kk + lg * 8);
                bf[i] = ldb(bs + (wc * 64 + i * 16 + lr) * 64 + kk + lg * 8);
            }
#pragma unroll
            for (int mi = 0; mi < 4; ++mi)
#pragma unroll
                for (int ni = 0; ni < 4; ++ni)
                    acc[mi][ni] = MFMA(af[mi], bf[ni], acc[mi][ni]);
        }
        __builtin_amdgcn_s_barrier();  // all waves done reading buf t&1
        if (t + 2 < NT) GSTAGE(t + 2);
    }
#undef GSTAGE

    if (MODE == 0) {  // plain f32 C, N=1024
        float* C = (float*)out0;
#pragma unroll
        for (int mi = 0; mi < 4; ++mi)
#pragma unroll
            for (int ni = 0; ni < 4; ++ni)
#pragma unroll
                for (int r = 0; r < 4; ++r) {
                    long row = m0 + wr * 64 + mi * 16 + lg * 4 + r;
                    long col = n0 + wc * 64 + ni * 16 + lr;
                    C[row * DM + col] = acc[mi][ni][r];
                }
    } else if (n0 < DM) {  // fused RoPE-Q (scaled by 0.125*log2e) -> bf16
        u16* Qb = (u16*)out0;
        const float SC = 0.18033688011112042f;
#pragma unroll
        for (int ni = 0; ni < 4; ++ni) {
            int col = (int)n0 + wc * 64 + ni * 16 + lr;
            int ii = (col & 63) >> 1;
#pragma unroll
            for (int mi = 0; mi < 4; ++mi) {
                long row0 = m0 + wr * 64 + mi * 16 + lg * 4;
#pragma unroll
                for (int r = 0; r < 4; ++r) {
                    int s = (int)(row0 + r) & (SEQ - 1);
                    float2 t = tab[s * 32 + ii];
                    float mine = acc[mi][ni][r];
                    float other = __shfl_xor(mine, 1);
                    float o = ((col & 1) ? (mine * t.x + other * t.y)
                                         : (mine * t.x - other * t.y)) * SC;
                    float oo = __shfl_xor(o, 1);
                    if (!(lr & 1))
                        *(unsigned*)(Qb + (row0 + r) * DM + col) = cvtpk(o, oo);
                }
            }
        }
    } else {  // KV block: cols 0-63 = K (RoPE, unscaled), cols 64-127 = V (transposed)
        u16* Kb = (u16*)out1;
        u16* VbT = (u16*)out2;
        if (wc == 0) {  // K half
#pragma unroll
            for (int ni = 0; ni < 4; ++ni) {
                int col = ni * 16 + lr;  // 0..63
                int ii = col >> 1;
#pragma unroll
                for (int mi = 0; mi < 4; ++mi) {
                    long row0 = m0 + wr * 64 + mi * 16 + lg * 4;
#pragma unroll
                    for (int r = 0; r < 4; ++r) {
                        int s = (int)(row0 + r) & (SEQ - 1);
                        float2 t = tab[s * 32 + ii];
                        float mine = acc[mi][ni][r];
                        float other = __shfl_xor(mine, 1);
                        float o = (col & 1) ? (mine * t.x + other * t.y)
                                            : (mine * t.x - other * t.y);
                        float oo = __shfl_xor(o, 1);
                        if (!(lr & 1))
                            *(unsigned*)(Kb + (row0 + r) * DK + col) = cvtpk(o, oo);
                    }
                }
            }
        } else {  // V half -> VbT[b][d][s]
#pragma unroll
            for (int ni = 0; ni < 4; ++ni) {
                int d = ni * 16 + lr;  // 0..63
#pragma unroll
                for (int mi = 0; mi < 4; ++mi) {
                    long row0 = m0 + wr * 64 + mi * 16 + lg * 4;
#pragma unroll
                    for (int r = 0; r < 4; ++r) {
                        long row = row0 + r;
                        long bb = row >> 11;
                        int s = (int)row & (SEQ - 1);
                        VbT[bb * DK * SEQ + (long)d * SEQ + s] = f2bf(acc[mi][ni][r]);
                    }
                }
            }
        }
    }
}

// ===== attention: 16 waves = 4 q-subs x 4 KV parities, 128KB ring-2, 4-way merge =====
// LDS slot (64KB) = 4 par x [K 8KB | V 8KB]; 2 slots. Swizzle: 16B slot ^= (row&7);
// linear LDS dest + inverse-swizzled global source (rule #21).
__device__ __forceinline__ void stage_step(u16* lds0, int slot, int kv0,
                                           const u16* Kbase, const u16* Vbase,
                                           int w16, int lane) {
    int ti = w16 >> 1;        // 0..7: tiles 0-3 = K(par), 4-7 = V(par)
    int hf = w16 & 1;         // half-tile: rows 32*hf..
    int p = ti & 3;
    int kvp = kv0 + p * 64;
    int rowin = lane >> 3, slotrow = lane & 7;
    u16* base = lds0 + slot * 32768 + p * 8192 + (ti < 4 ? 0 : 4096) + hf * 2048;
    if (ti < 4) {  // K tile: row = kv index
#pragma unroll
        for (int c = 0; c < 4; ++c) {
            int row = hf * 32 + c * 8 + rowin;
            gload16(Kbase + (long)(kvp + row) * DK + ((slotrow ^ (row & 7)) * 8),
                    base + c * 512);
        }
    } else {  // V tile: row = d
#pragma unroll
        for (int c = 0; c < 4; ++c) {
            int row = hf * 32 + c * 8 + rowin;
            gload16(Vbase + (long)row * SEQ + kvp + ((slotrow ^ (row & 7)) * 8),
                    base + c * 512);
        }
    }
}

__device__ __forceinline__ bf16x8 lds_frag(const u16* tile, int row, int slot) {
    return ldb(tile + row * 64 + ((slot ^ (row & 7)) * 8));
}

// Swapped QK^T: S^T[kv][q] = mfma(K, Q^T); crow(r,hi) = (r&3) + 8*(r>>2) + 4*hi.
// Swapped PV: O^T[d][q] = mfma(V^T, P^T). log2-domain softmax, deferred max (T13).
template <bool MASKED>
__device__ __forceinline__ void attn_tile(int kv0, int q, int lq, int hi,
                                          const u16* Kt, const u16* Vt,
                                          const bf16x8 qf[4],
                                          f32x16& o0, f32x16& o1,
                                          float& m, float& lsum) {
    f32x16 s0 = {}, s1 = {};
    __builtin_amdgcn_s_setprio(1);
#pragma unroll
    for (int ks = 0; ks < 4; ++ks) {
        s0 = MFMA32(lds_frag(Kt, lq, hi + 2 * ks), qf[ks], s0);
        s1 = MFMA32(lds_frag(Kt, lq + 32, hi + 2 * ks), qf[ks], s1);
    }
    __builtin_amdgcn_s_setprio(0);
    if (MASKED) {
#pragma unroll
        for (int r = 0; r < 16; ++r) {
            int crow = (r & 3) + 8 * (r >> 2) + 4 * hi;
            if (kv0 + crow > q) s0[r] = -3e38f;
            if (kv0 + 32 + crow > q) s1[r] = -3e38f;
        }
    }
    float t[8];
#pragma unroll
    for (int j = 0; j < 8; ++j)
        t[j] = fmaxf(fmaxf(s0[j], s0[j + 8]), fmaxf(s1[j], s1[j + 8]));
    float pmax = fmaxf(fmaxf(fmaxf(t[0], t[4]), fmaxf(t[1], t[5])),
                       fmaxf(fmaxf(t[2], t[6]), fmaxf(t[3], t[7])));
    pmax = fmaxf(pmax, __shfl_xor(pmax, 32));
    if (__any(pmax > m + 8.f)) {
        float mnew = fmaxf(m, pmax);
        float fac = fexp2(m - mnew);
        m = mnew;
        lsum *= fac;
        o0 *= fac;
        o1 *= fac;
    }
    float p0[16], p1[16];
#pragma unroll
    for (int r = 0; r < 16; ++r) {
        p0[r] = fexp2(s0[r] - m);
        p1[r] = fexp2(s1[r] - m);
    }
    float su[8];
#pragma unroll
    for (int j = 0; j < 8; ++j)
        su[j] = (p0[j] + p0[j + 8]) + (p1[j] + p1[j + 8]);
    float psum = ((su[0] + su[4]) + (su[1] + su[5])) + ((su[2] + su[6]) + (su[3] + su[7]));
    psum += __shfl_xor(psum, 32);
    lsum += psum;
    bf16x8 pa[4];
#pragma unroll
    for (int g = 0; g < 2; ++g) {
        unsigned a0 = cvtpk(p0[g * 8 + 0], p0[g * 8 + 1]);
        unsigned b0 = cvtpk(p0[g * 8 + 4], p0[g * 8 + 5]);
        swap32(a0, b0);
        unsigned a1 = cvtpk(p0[g * 8 + 2], p0[g * 8 + 3]);
        unsigned b1 = cvtpk(p0[g * 8 + 6], p0[g * 8 + 7]);
        swap32(a1, b1);
        u32x4 u = {a0, a1, b0, b1};
        pa[g] = __builtin_bit_cast(bf16x8, u);
    }
#pragma unroll
    for (int g = 0; g < 2; ++g) {
        unsigned a0 = cvtpk(p1[g * 8 + 0], p1[g * 8 + 1]);
        unsigned b0 = cvtpk(p1[g * 8 + 4], p1[g * 8 + 5]);
        swap32(a0, b0);
        unsigned a1 = cvtpk(p1[g * 8 + 2], p1[g * 8 + 3]);
        unsigned b1 = cvtpk(p1[g * 8 + 6], p1[g * 8 + 7]);
        swap32(a1, b1);
        u32x4 u = {a0, a1, b0, b1};
        pa[2 + g] = __builtin_bit_cast(bf16x8, u);
    }
    __builtin_amdgcn_s_setprio(1);
#pragma unroll
    for (int ks = 0; ks < 4; ++ks) {
        o0 = MFMA32(lds_frag(Vt, lq, hi + 2 * ks), pa[ks], o0);
        o1 = MFMA32(lds_frag(Vt, lq + 32, hi + 2 * ks), pa[ks], o1);
    }
    __builtin_amdgcn_s_setprio(0);
}

// grid: 512 blocks x 1024 thr (16 waves = 4 q-subs x 4 parities), 1 block/CU.
// 2 dispatch rounds: qt odd-desc (round 1) then even-desc (round 2) so early
// finishers backfill with anti-correlated lengths. Per step: vmcnt(4) -> barrier ->
// compute tile st*256+par*64 -> barrier -> stage step st+2. End: 4-way merge.
__global__ __launch_bounds__(1024, 4) void k_attn(const u16* __restrict__ Qb,
                                                  const u16* __restrict__ Kb,
                                                  const u16* __restrict__ VbT,
                                                  u16* __restrict__ Ob) {
    extern __shared__ __align__(16) u16 alds[];  // 128KB: 2 slots x 4 par x (K|V)
    u16* lds0 = alds;
    int id = blockIdx.x;
    int h = id & 15, b = (id >> 4) & 1;
    int qslot = id >> 5;  // 0..15
    int qt = qslot < 8 ? 15 - 2 * qslot : 30 - 2 * qslot;
    int qb0 = qt * 128;
    int tid = threadIdx.x;
    int w16 = tid >> 6, lane = tid & 63;
    int w = w16 & 3, par = w16 >> 2;
    int lq = lane & 31, hi = lane >> 5;
    int q0w = qb0 + 32 * w;
    int q = q0w + lq;
    const u16* Qp = Qb + (long)(b * SEQ + q) * DM + h * DK + hi * 8;
    bf16x8 qf[4];
#pragma unroll
    for (int ks = 0; ks < 4; ++ks) qf[ks] = ldb(Qp + ks * 16);
    const u16* Kbase = Kb + (long)b * SEQ * DK;
    const u16* Vbase = VbT + (long)b * DK * SEQ;
    f32x16 o0 = {}, o1 = {};
    float m = -1e30f, lsum = 0.f;

    int nstep = (qt + 2) >> 1;  // 256-KV super-steps covering [0, qb0+128)
    stage_step(lds0, 0, 0, Kbase, Vbase, w16, lane);
    if (nstep > 1) stage_step(lds0, 1, 256, Kbase, Vbase, w16, lane);
    for (int st = 0; st < nstep; ++st) {
        if (st + 1 < nstep) {
            asm volatile("s_waitcnt vmcnt(4)" ::: "memory");  // step st landed (mine)
        } else {
            asm volatile("s_waitcnt vmcnt(0)" ::: "memory");
        }
        __builtin_amdgcn_s_barrier();  // step st landed (all waves)
        int kv0 = st * 256 + par * 64;
        const u16* Kt = lds0 + (st & 1) * 32768 + par * 8192;
        const u16* Vt = Kt + 4096;
        if (kv0 <= q0w + 31) {
            if (kv0 + 63 <= q0w)
                attn_tile<false>(kv0, q, lq, hi, Kt, Vt, qf, o0, o1, m, lsum);
            else
                attn_tile<true>(kv0, q, lq, hi, Kt, Vt, qf, o0, o1, m, lsum);
        }
        __builtin_amdgcn_s_barrier();  // all waves done reading slot st&1
        if (st + 2 < nstep)
            stage_step(lds0, st & 1, (st + 2) * 256, Kbase, Vbase, w16, lane);
    }

    // ---- 4-way split-KV merge: pars 1-3 publish (O, m, l); par 0 combines ----
    __syncthreads();
    float* mrg = (float*)lds0;  // 3 x 256 x 34 floats = 104448 B
    if (par != 0) {
        float* dst = mrg + ((par - 1) * 256 + w * 64 + lane) * 34;
#pragma unroll
        for (int r = 0; r < 16; ++r) { dst[r] = o0[r]; dst[16 + r] = o1[r]; }
        dst[32] = m;
        dst[33] = lsum;
    }
    __syncthreads();
    if (par == 0) {
        const float* s1 = mrg + (0 * 256 + w * 64 + lane) * 34;
        const float* s2 = mrg + (1 * 256 + w * 64 + lane) * 34;
        const float* s3 = mrg + (2 * 256 + w * 64 + lane) * 34;
        float m1 = s1[32], m2 = s2[32], m3 = s3[32];
        float mstar = fmaxf(fmaxf(m, m1), fmaxf(m2, m3));
        float f0 = fexp2(m - mstar), f1 = fexp2(m1 - mstar);
        float f2 = fexp2(m2 - mstar), f3 = fexp2(m3 - mstar);
        float linv = 1.f / (lsum * f0 + s1[33] * f1 + s2[33] * f2 + s3[33] * f3);
#pragma unroll
        for (int r = 0; r < 16; ++r) {
            o0[r] = (o0[r] * f0 + s1[r] * f1 + s2[r] * f2 + s3[r] * f3) * linv;
            o1[r] = (o1[r] * f0 + s1[16 + r] * f1 + s2[16 + r] * f2 + s3[16 + r] * f3) * linv;
        }
        u16* Ot = lds0 + 52224 + w * 2304;  // 32 x 72 u16 per q-sub (disjoint from mrg)
#pragma unroll
        for (int rq = 0; rq < 4; ++rq) {
            uint2 u0, u1;
            u0.x = cvtpk(o0[4 * rq + 0], o0[4 * rq + 1]);
            u0.y = cvtpk(o0[4 * rq + 2], o0[4 * rq + 3]);
            u1.x = cvtpk(o1[4 * rq + 0], o1[4 * rq + 1]);
            u1.y = cvtpk(o1[4 * rq + 2], o1[4 * rq + 3]);
            *(uint2*)&Ot[lq * 72 + rq * 8 + hi * 4] = u0;
            *(uint2*)&Ot[lq * 72 + 32 + rq * 8 + hi * 4] = u1;
        }
#pragma unroll
        for (int i2 = 0; i2 < 4; ++i2) {
            int c = i2 * 64 + lane;
            int row = c >> 3, col = (c & 7) * 8;
            u16x8 v = *(const u16x8*)&Ot[row * 72 + col];
            *(u16x8*)(Ob + (long)(b * SEQ + q0w + row) * DM + h * DK + col) = v;
        }
    }
}

extern "C" void kernel_launch(void* const* d_in, const int* in_sizes, int n_in,
                              void* d_out, int out_size, void* d_ws, size_t ws_size,
                              hipStream_t stream) {
    const float* x = (const float*)d_in[0];
    const float* Wq = (const float*)d_in[1];
    const float* Wk = (const float*)d_in[2];
    const float* Wv = (const float*)d_in[3];
    const float* Wo = (const float*)d_in[4];
    float* out = (float*)d_out;

    const int M = 2 * SEQ;  // 4096 rows
    char* p = (char*)d_ws;
    u16* xb = (u16*)p;        p += (size_t)M * DM * 2;          // 8 MB
    u16* WqkvT = (u16*)p;     p += (size_t)(DM + 2 * DK) * DM * 2;  // 2.25 MB
    u16* WobT = (u16*)p;      p += (size_t)DM * DM * 2;         // 2 MB
    u16* Qb = (u16*)p;        p += (size_t)M * DM * 2;          // 8 MB
    u16* Kb = (u16*)p;        p += (size_t)M * DK * 2;          // 512 KB
    u16* VbT = (u16*)p;       p += (size_t)M * DK * 2;          // 512 KB
    u16* Ob = (u16*)p;        p += (size_t)M * DM * 2;          // 8 MB
    float2* tab = (float2*)p; p += (size_t)SEQ * 32 * 8;        // 512 KB

    const size_t GEMM_LDS = 2 * 2 * 8192 * sizeof(u16);  // 64 KB -> 2 blocks/CU
    const size_t ATTN_LDS = 131072;                      // 128 KB -> 1 block/CU

    // 1) fused prep: cvt + trig + weight transposes (one launch)
    k_prep<<<NB_CVT + NB_TRIG + NB_TQ + NB_TK + NB_TV + NB_TO, 256, 0, stream>>>(
        x, xb, tab, Wq, Wk, Wv, WqkvT, Wo, WobT);

    // 2) fused QKV projection: N=1152; epi = RoPE-Q -> Qb, RoPE-K -> Kb, V^T -> VbT
    k_gemm_r2<1><<<dim3((DM + 2 * DK) / 128, M / 128), 256, GEMM_LDS, stream>>>(
        xb, WqkvT, Qb, Kb, VbT, tab);

    // 3) attention (16-wave blocks, 4-way split-KV, 128KB ring-2)
    k_attn<<<dim3(2 * NH * (SEQ / 128)), 1024, ATTN_LDS, stream>>>(Qb, Kb, VbT, Ob);

    // 4) output projection -> d_out
    k_gemm_r2<0><<<dim3(DM / 128, M / 128), 256, GEMM_LDS, stream>>>(
        Ob, WobT, out, nullptr, nullptr, nullptr);
}

// Round 15
// 97.757 us; speedup vs baseline: 1.0222x; 1.0222x over previous
//
#include <hip/hip_runtime.h>

#define DM 1024
#define NH 16
#define DK 64
#define SEQ 2048

typedef __attribute__((ext_vector_type(8))) __bf16 bf16x8;
typedef __attribute__((ext_vector_type(4))) float f32x4;
typedef __attribute__((ext_vector_type(16))) float f32x16;
typedef __attribute__((ext_vector_type(8))) unsigned short u16x8;
typedef __attribute__((ext_vector_type(4))) unsigned int u32x4;
typedef unsigned short u16;

#define MFMA(a, b, c) __builtin_amdgcn_mfma_f32_16x16x32_bf16(a, b, c, 0, 0, 0)
#define MFMA32(a, b, c) __builtin_amdgcn_mfma_f32_32x32x16_bf16(a, b, c, 0, 0, 0)

__device__ __forceinline__ u16 f2bf(float f) {
    unsigned u = __builtin_bit_cast(unsigned, f);
    u = (u + 0x7FFFu + ((u >> 16) & 1u)) >> 16;
    return (u16)u;
}

__device__ __forceinline__ bf16x8 ldb(const u16* p) {
    u16x8 v = *(const u16x8*)p;
    return __builtin_bit_cast(bf16x8, v);
}

__device__ __forceinline__ unsigned cvtpk(float a, float b) {
    unsigned r;
    asm("v_cvt_pk_bf16_f32 %0, %1, %2" : "=v"(r) : "v"(a), "v"(b));
    return r;
}

__device__ __forceinline__ void swap32(unsigned& a, unsigned& b) {
    asm volatile("v_permlane32_swap_b32 %0, %1" : "+v"(a), "+v"(b));
}

__device__ __forceinline__ float fexp2(float x) {
    return __builtin_amdgcn_exp2f(x);
}

// async global->LDS, 16B per lane, LDS dest = wave-uniform base + lane*16
__device__ __forceinline__ void gload16(const u16* g, u16* l) {
    __builtin_amdgcn_global_load_lds(
        (const __attribute__((address_space(1))) unsigned int*)g,
        (__attribute__((address_space(3))) unsigned int*)l, 16, 0, 0);
}

// ================= fused prep: cvt + trig table + 4 weight transposes =================
#define NB_CVT 4096
#define NB_TRIG 256
#define NB_TQ 1024
#define NB_TK 64
#define NB_TV 64
#define NB_TO 1024

__device__ __forceinline__ void do_transpose(const float* __restrict__ W,
                                             u16* __restrict__ WT, int ldW, int K,
                                             int bx, int by, float (*t)[33]) {
    int n0 = bx * 32, k0 = by * 32;
    int tx = threadIdx.x & 31, ty = threadIdx.x >> 5;
#pragma unroll
    for (int i = 0; i < 32; i += 8)
        t[ty + i][tx] = W[(long)(k0 + ty + i) * ldW + n0 + tx];
    __syncthreads();
#pragma unroll
    for (int i = 0; i < 32; i += 8)
        WT[(long)(n0 + ty + i) * K + k0 + tx] = f2bf(t[tx][ty + i]);
}

__global__ __launch_bounds__(256) void k_prep(const float* __restrict__ x,
                                              u16* __restrict__ xb,
                                              float2* __restrict__ tab,
                                              const float* __restrict__ Wq,
                                              const float* __restrict__ Wk,
                                              const float* __restrict__ Wv,
                                              u16* __restrict__ WqkvT,
                                              const float* __restrict__ Wo,
                                              u16* __restrict__ WobT) {
    __shared__ float tsh[32][33];
    int blk = blockIdx.x;
    if (blk < NB_CVT) {  // f32 -> bf16 convert, x4 vectorized
        int i = blk * 256 + threadIdx.x;
        float4 v = ((const float4*)x)[i];
        ushort4 o;
        o.x = f2bf(v.x); o.y = f2bf(v.y); o.z = f2bf(v.z); o.w = f2bf(v.w);
        ((ushort4*)xb)[i] = o;
        return;
    }
    blk -= NB_CVT;
    if (blk < NB_TRIG) {  // sincos table tab[s][i]
        int idx = blk * 256 + threadIdx.x;
        int i = idx & 31, s = idx >> 5;
        float theta = exp2f(-(float)i * 0.4152410118609203f);  // 10000^(-2i/64)
        float sn, cs;
        sincosf((float)s * theta, &sn, &cs);
        tab[idx] = make_float2(cs, sn);
        return;
    }
    blk -= NB_TRIG;
    if (blk < NB_TQ) { do_transpose(Wq, WqkvT, DM, DM, blk & 31, blk >> 5, tsh); return; }
    blk -= NB_TQ;
    if (blk < NB_TK) { do_transpose(Wk, WqkvT + (size_t)DM * DM, DK, DM, blk & 1, blk >> 1, tsh); return; }
    blk -= NB_TK;
    if (blk < NB_TV) { do_transpose(Wv, WqkvT + (size_t)(DM + DK) * DM, DK, DM, blk & 1, blk >> 1, tsh); return; }
    blk -= NB_TV;
    do_transpose(Wo, WobT, DM, DM, blk & 31, blk >> 5, tsh);
}

// ========== ring-2 GEMM, 8 waves (2 waves/SIMD), counted vmcnt ==========
// 128x128 tile, BK=64, 512 thr; wave (wr,wc) = (w>>2, w&3) owns 64x32 out.
// Per wave 4 gload16/K-step -> steady vmcnt(4), vmcnt(0) last; 64KB LDS.
// MODE 0: plain f32 C (N=1024). MODE 1: fused QKV epi (N=1152) — n-blocks 0..7 =
// RoPE-Q -> bf16 Qb; n-block 8 = RoPE-K -> Kb (cols 0-63) + V^T -> VbT (64-127).
template <int MODE>
__global__ __launch_bounds__(512) void k_gemm_r2(const u16* __restrict__ A,
                                                 const u16* __restrict__ BT,
                                                 void* __restrict__ out0,
                                                 void* __restrict__ out1,
                                                 void* __restrict__ out2,
                                                 const float2* __restrict__ tab) {
    extern __shared__ __align__(16) u16 lds[];  // [2][A:8192] ++ [2][B:8192] (u16)
    const int NT = 16;                          // K=1024 / 64
    const int K = DM;
    int tid = threadIdx.x;
    int w = tid >> 6, lane = tid & 63, lg = lane >> 4, lr = lane & 15;
    int wr = w >> 2, wc = w & 3;
    long m0 = (long)blockIdx.y * 128, n0 = (long)blockIdx.x * 128;
    int lrow = lane >> 3, lcol = (lane & 7) * 8;

    f32x4 acc[4][2] = {};

#define GSTAGE(t)                                                                   \
    {                                                                               \
        u16* as_ = lds + ((t) & 1) * 8192;                                          \
        u16* bs_ = lds + 16384 + ((t) & 1) * 8192;                                  \
        int k0_ = (t) * 64;                                                         \
        _Pragma("unroll") for (int it = 0; it < 2; ++it) {                          \
            int row = w * 16 + it * 8;                                              \
            gload16(A + (m0 + row + lrow) * K + k0_ + lcol, as_ + row * 64);        \
            gload16(BT + (n0 + row + lrow) * K + k0_ + lcol, bs_ + row * 64);       \
        }                                                                           \
    }

    GSTAGE(0);
    GSTAGE(1);
    for (int t = 0; t < NT; ++t) {
        if (t + 1 < NT) {
            asm volatile("s_waitcnt vmcnt(4)" ::: "memory");  // K-step t landed (mine)
        } else {
            asm volatile("s_waitcnt vmcnt(0)" ::: "memory");
        }
        __builtin_amdgcn_s_barrier();  // K-step t landed (all waves)
        const u16* as = lds + (t & 1) * 8192;
        const u16* bs = lds + 16384 + (t & 1) * 8192;
#pragma unroll
        for (int kk = 0; kk < 64; kk += 32) {
            bf16x8 af[4], bf[2];
#pragma unroll
            for (int i = 0; i < 4; ++i)
                af[i] = ldb(as + (wr * 64 + i * 16 + lr) * 64 + kk + lg * 8);
#pragma unroll
            for (int j = 0; j < 2; ++j)
                bf[j] = ldb(bs + (wc * 32 + j * 16 + lr) * 64 + kk + lg * 8);
#pragma unroll
            for (int mi = 0; mi < 4; ++mi)
#pragma unroll
                for (int ni = 0; ni < 2; ++ni)
                    acc[mi][ni] = MFMA(af[mi], bf[ni], acc[mi][ni]);
        }
        __builtin_amdgcn_s_barrier();  // all waves done reading buf t&1
        if (t + 2 < NT) GSTAGE(t + 2);
    }
#undef GSTAGE

    if (MODE == 0) {  // plain f32 C, N=1024
        float* C = (float*)out0;
#pragma unroll
        for (int mi = 0; mi < 4; ++mi)
#pragma unroll
            for (int ni = 0; ni < 2; ++ni)
#pragma unroll
                for (int r = 0; r < 4; ++r) {
                    long row = m0 + wr * 64 + mi * 16 + lg * 4 + r;
                    long col = n0 + wc * 32 + ni * 16 + lr;
                    C[row * DM + col] = acc[mi][ni][r];
                }
    } else if (n0 < DM) {  // fused RoPE-Q (scaled by 0.125*log2e) -> bf16
        u16* Qb = (u16*)out0;
        const float SC = 0.18033688011112042f;
#pragma unroll
        for (int ni = 0; ni < 2; ++ni) {
            int col = (int)n0 + wc * 32 + ni * 16 + lr;
            int ii = (col & 63) >> 1;
#pragma unroll
            for (int mi = 0; mi < 4; ++mi) {
                long row0 = m0 + wr * 64 + mi * 16 + lg * 4;
#pragma unroll
                for (int r = 0; r < 4; ++r) {
                    int s = (int)(row0 + r) & (SEQ - 1);
                    float2 t = tab[s * 32 + ii];
                    float mine = acc[mi][ni][r];
                    float other = __shfl_xor(mine, 1);
                    float o = ((col & 1) ? (mine * t.x + other * t.y)
                                         : (mine * t.x - other * t.y)) * SC;
                    float oo = __shfl_xor(o, 1);
                    if (!(lr & 1))
                        *(unsigned*)(Qb + (row0 + r) * DM + col) = cvtpk(o, oo);
                }
            }
        }
    } else {  // KV block: cols 0-63 = K (RoPE, unscaled), cols 64-127 = V (transposed)
        u16* Kb = (u16*)out1;
        u16* VbT = (u16*)out2;
        if (wc < 2) {  // K half
#pragma unroll
            for (int ni = 0; ni < 2; ++ni) {
                int col = wc * 32 + ni * 16 + lr;  // 0..63
                int ii = col >> 1;
#pragma unroll
                for (int mi = 0; mi < 4; ++mi) {
                    long row0 = m0 + wr * 64 + mi * 16 + lg * 4;
#pragma unroll
                    for (int r = 0; r < 4; ++r) {
                        int s = (int)(row0 + r) & (SEQ - 1);
                        float2 t = tab[s * 32 + ii];
                        float mine = acc[mi][ni][r];
                        float other = __shfl_xor(mine, 1);
                        float o = (col & 1) ? (mine * t.x + other * t.y)
                                            : (mine * t.x - other * t.y);
                        float oo = __shfl_xor(o, 1);
                        if (!(lr & 1))
                            *(unsigned*)(Kb + (row0 + r) * DK + col) = cvtpk(o, oo);
                    }
                }
            }
        } else {  // V half -> VbT[b][d][s]
#pragma unroll
            for (int ni = 0; ni < 2; ++ni) {
                int d = (wc - 2) * 32 + ni * 16 + lr;  // 0..63
#pragma unroll
                for (int mi = 0; mi < 4; ++mi) {
                    long row0 = m0 + wr * 64 + mi * 16 + lg * 4;
#pragma unroll
                    for (int r = 0; r < 4; ++r) {
                        long row = row0 + r;
                        long bb = row >> 11;
                        int s = (int)row & (SEQ - 1);
                        VbT[bb * DK * SEQ + (long)d * SEQ + s] = f2bf(acc[mi][ni][r]);
                    }
                }
            }
        }
    }
}

// ============ attention: 8 waves = 4 q-subs x {even,odd} KV tiles, split-KV merge ============
// LDS: 2 pair-slots x [Ke|Ve|Ko|Vo] 8KB tiles = 64KB. Swizzle: 16B slot ^= (row&7);
// linear LDS dest + inverse-swizzled global source (rule #21).
__device__ __forceinline__ void stage_pair(u16* lds0, int pslot, int kv0,
                                           const u16* Kbase, const u16* Vbase,
                                           int w8, int lane) {
    int row = w8 * 8 + (lane >> 3), slot = lane & 7;
    int sw = (slot ^ (row & 7)) * 8;
    u16* base = lds0 + pslot * 16384 + w8 * 512;
    gload16(Kbase + (long)(kv0 + row) * DK + sw, base);
    gload16(Vbase + (long)row * SEQ + kv0 + sw, base + 4096);
    gload16(Kbase + (long)(kv0 + 64 + row) * DK + sw, base + 8192);
    gload16(Vbase + (long)row * SEQ + kv0 + 64 + sw, base + 12288);
}

__device__ __forceinline__ bf16x8 lds_frag(const u16* tile, int row, int slot) {
    return ldb(tile + row * 64 + ((slot ^ (row & 7)) * 8));
}

// Swapped QK^T: S^T[kv][q] = mfma(K, Q^T); crow(r,hi) = (r&3) + 8*(r>>2) + 4*hi.
// Swapped PV: O^T[d][q] = mfma(V^T, P^T). log2-domain softmax, deferred max (T13).
template <bool MASKED>
__device__ __forceinline__ void attn_tile(int kv0, int q, int lq, int hi,
                                          const u16* Kt, const u16* Vt,
                                          const bf16x8 qf[4],
                                          f32x16& o0, f32x16& o1,
                                          float& m, float& lsum) {
    f32x16 s0 = {}, s1 = {};
    __builtin_amdgcn_s_setprio(1);
#pragma unroll
    for (int ks = 0; ks < 4; ++ks) {
        s0 = MFMA32(lds_frag(Kt, lq, hi + 2 * ks), qf[ks], s0);
        s1 = MFMA32(lds_frag(Kt, lq + 32, hi + 2 * ks), qf[ks], s1);
    }
    __builtin_amdgcn_s_setprio(0);
    if (MASKED) {
#pragma unroll
        for (int r = 0; r < 16; ++r) {
            int crow = (r & 3) + 8 * (r >> 2) + 4 * hi;
            if (kv0 + crow > q) s0[r] = -3e38f;
            if (kv0 + 32 + crow > q) s1[r] = -3e38f;
        }
    }
    float t[8];
#pragma unroll
    for (int j = 0; j < 8; ++j)
        t[j] = fmaxf(fmaxf(s0[j], s0[j + 8]), fmaxf(s1[j], s1[j + 8]));
    float pmax = fmaxf(fmaxf(fmaxf(t[0], t[4]), fmaxf(t[1], t[5])),
                       fmaxf(fmaxf(t[2], t[6]), fmaxf(t[3], t[7])));
    pmax = fmaxf(pmax, __shfl_xor(pmax, 32));
    if (__any(pmax > m + 8.f)) {
        float mnew = fmaxf(m, pmax);
        float fac = fexp2(m - mnew);
        m = mnew;
        lsum *= fac;
        o0 *= fac;
        o1 *= fac;
    }
    float p0[16], p1[16];
#pragma unroll
    for (int r = 0; r < 16; ++r) {
        p0[r] = fexp2(s0[r] - m);
        p1[r] = fexp2(s1[r] - m);
    }
    float su[8];
#pragma unroll
    for (int j = 0; j < 8; ++j)
        su[j] = (p0[j] + p0[j + 8]) + (p1[j] + p1[j + 8]);
    float psum = ((su[0] + su[4]) + (su[1] + su[5])) + ((su[2] + su[6]) + (su[3] + su[7]));
    psum += __shfl_xor(psum, 32);
    lsum += psum;
    bf16x8 pa[4];
#pragma unroll
    for (int g = 0; g < 2; ++g) {
        unsigned a0 = cvtpk(p0[g * 8 + 0], p0[g * 8 + 1]);
        unsigned b0 = cvtpk(p0[g * 8 + 4], p0[g * 8 + 5]);
        swap32(a0, b0);
        unsigned a1 = cvtpk(p0[g * 8 + 2], p0[g * 8 + 3]);
        unsigned b1 = cvtpk(p0[g * 8 + 6], p0[g * 8 + 7]);
        swap32(a1, b1);
        u32x4 u = {a0, a1, b0, b1};
        pa[g] = __builtin_bit_cast(bf16x8, u);
    }
#pragma unroll
    for (int g = 0; g < 2; ++g) {
        unsigned a0 = cvtpk(p1[g * 8 + 0], p1[g * 8 + 1]);
        unsigned b0 = cvtpk(p1[g * 8 + 4], p1[g * 8 + 5]);
        swap32(a0, b0);
        unsigned a1 = cvtpk(p1[g * 8 + 2], p1[g * 8 + 3]);
        unsigned b1 = cvtpk(p1[g * 8 + 6], p1[g * 8 + 7]);
        swap32(a1, b1);
        u32x4 u = {a0, a1, b0, b1};
        pa[2 + g] = __builtin_bit_cast(bf16x8, u);
    }
    __builtin_amdgcn_s_setprio(1);
#pragma unroll
    for (int ks = 0; ks < 4; ++ks) {
        o0 = MFMA32(lds_frag(Vt, lq, hi + 2 * ks), pa[ks], o0);
        o1 = MFMA32(lds_frag(Vt, lq + 32, hi + 2 * ks), pa[ks], o1);
    }
    __builtin_amdgcn_s_setprio(0);
}

// grid: 512 blocks x 512 thr. Waves 0-3: even KV tiles; waves 4-7: odd tiles, same
// 128 q-rows. Per pair p: vmcnt(4) -> barrier -> compute tile 2p+par -> barrier ->
// stage pair p+2. End: split-KV merge.
__global__ __launch_bounds__(512) void k_attn(const u16* __restrict__ Qb,
                                              const u16* __restrict__ Kb,
                                              const u16* __restrict__ VbT,
                                              u16* __restrict__ Ob) {
    __shared__ __align__(16) u16 lds[2][4][4096];  // [pair-slot][Ke|Ve|Ko|Vo] = 64KB
    u16* lds0 = &lds[0][0][0];
    int id = blockIdx.x;
    int h = id & 15, b = (id >> 4) & 1;
    int qslot = id >> 5;                               // 0..15
    int qt = qslot < 8 ? qslot * 2 : 31 - qslot * 2;   // co-resident pair sums const
    int qb0 = qt * 128;
    int tid = threadIdx.x;
    int w8 = tid >> 6, lane = tid & 63;
    int w = w8 & 3, par = w8 >> 2;  // q-sub, even/odd tile parity
    int lq = lane & 31, hi = lane >> 5;
    int q0w = qb0 + 32 * w;
    int q = q0w + lq;
    const u16* Qp = Qb + (long)(b * SEQ + q) * DM + h * DK + hi * 8;
    bf16x8 qf[4];
#pragma unroll
    for (int ks = 0; ks < 4; ++ks) qf[ks] = ldb(Qp + ks * 16);
    const u16* Kbase = Kb + (long)b * SEQ * DK;
    const u16* Vbase = VbT + (long)b * DK * SEQ;
    f32x16 o0 = {}, o1 = {};
    float m = -1e30f, lsum = 0.f;

    int npair = qt + 1;  // nt = 2*qt+2 tiles = qt+1 pairs of 64-kv tiles
    stage_pair(lds0, 0, 0, Kbase, Vbase, w8, lane);
    if (npair > 1) stage_pair(lds0, 1, 128, Kbase, Vbase, w8, lane);
    for (int p = 0; p < npair; ++p) {
        if (p + 1 < npair) {
            asm volatile("s_waitcnt vmcnt(4)" ::: "memory");  // pair p landed (mine)
        } else {
            asm volatile("s_waitcnt vmcnt(0)" ::: "memory");
        }
        __builtin_amdgcn_s_barrier();  // pair p landed (all waves)
        int t = 2 * p + par;
        int kv0 = t * 64;
        const u16* Kt = lds0 + (p & 1) * 16384 + par * 8192;
        const u16* Vt = Kt + 4096;
        if (kv0 <= q0w + 31) {
            if (kv0 + 63 <= q0w)
                attn_tile<false>(kv0, q, lq, hi, Kt, Vt, qf, o0, o1, m, lsum);
            else
                attn_tile<true>(kv0, q, lq, hi, Kt, Vt, qf, o0, o1, m, lsum);
        }
        __builtin_amdgcn_s_barrier();  // all waves done reading pair p's slots
        if (p + 2 < npair)
            stage_pair(lds0, p & 1, (2 * p + 4) * 64, Kbase, Vbase, w8, lane);
    }

    // ---- split-KV merge: odd waves publish (O, m, l); even waves combine ----
    __syncthreads();
    float* mrg = (float*)lds0;  // floats [0, 8704); Ot region starts at u16 20480
    if (par == 1) {
        float* dst = mrg + (w * 64 + lane) * 34;
#pragma unroll
        for (int r = 0; r < 16; ++r) { dst[r] = o0[r]; dst[16 + r] = o1[r]; }
        dst[32] = m;
        dst[33] = lsum;
    }
    __syncthreads();
    if (par == 0) {
        const float* src = mrg + (w * 64 + lane) * 34;
        float m_o = src[32], l_o = src[33];
        float mstar = fmaxf(m, m_o);
        float fe = fexp2(m - mstar), fo = fexp2(m_o - mstar);
        float linv = 1.f / (lsum * fe + l_o * fo);
#pragma unroll
        for (int r = 0; r < 16; ++r) {
            o0[r] = (o0[r] * fe + src[r] * fo) * linv;
            o1[r] = (o1[r] * fe + src[16 + r] * fo) * linv;
        }
        u16* Ot = lds0 + 20480 + w * 2304;  // 32 x 72 u16 per wave (disjoint from mrg)
#pragma unroll
        for (int rq = 0; rq < 4; ++rq) {
            uint2 u0, u1;
            u0.x = cvtpk(o0[4 * rq + 0], o0[4 * rq + 1]);
            u0.y = cvtpk(o0[4 * rq + 2], o0[4 * rq + 3]);
            u1.x = cvtpk(o1[4 * rq + 0], o1[4 * rq + 1]);
            u1.y = cvtpk(o1[4 * rq + 2], o1[4 * rq + 3]);
            *(uint2*)&Ot[lq * 72 + rq * 8 + hi * 4] = u0;
            *(uint2*)&Ot[lq * 72 + 32 + rq * 8 + hi * 4] = u1;
        }
#pragma unroll
        for (int i2 = 0; i2 < 4; ++i2) {
            int c = i2 * 64 + lane;
            int row = c >> 3, col = (c & 7) * 8;
            u16x8 v = *(const u16x8*)&Ot[row * 72 + col];
            *(u16x8*)(Ob + (long)(b * SEQ + q0w + row) * DM + h * DK + col) = v;
        }
    }
}

extern "C" void kernel_launch(void* const* d_in, const int* in_sizes, int n_in,
                              void* d_out, int out_size, void* d_ws, size_t ws_size,
                              hipStream_t stream) {
    const float* x = (const float*)d_in[0];
    const float* Wq = (const float*)d_in[1];
    const float* Wk = (const float*)d_in[2];
    const float* Wv = (const float*)d_in[3];
    const float* Wo = (const float*)d_in[4];
    float* out = (float*)d_out;

    const int M = 2 * SEQ;  // 4096 rows
    char* p = (char*)d_ws;
    u16* xb = (u16*)p;        p += (size_t)M * DM * 2;          // 8 MB
    u16* WqkvT = (u16*)p;     p += (size_t)(DM + 2 * DK) * DM * 2;  // 2.25 MB
    u16* WobT = (u16*)p;      p += (size_t)DM * DM * 2;         // 2 MB
    u16* Qb = (u16*)p;        p += (size_t)M * DM * 2;          // 8 MB
    u16* Kb = (u16*)p;        p += (size_t)M * DK * 2;          // 512 KB
    u16* VbT = (u16*)p;       p += (size_t)M * DK * 2;          // 512 KB
    u16* Ob = (u16*)p;        p += (size_t)M * DM * 2;          // 8 MB
    float2* tab = (float2*)p; p += (size_t)SEQ * 32 * 8;        // 512 KB

    const size_t GEMM_LDS = 2 * 2 * 8192 * sizeof(u16);  // 64 KB

    // 1) fused prep: cvt + trig + weight transposes (one launch)
    k_prep<<<NB_CVT + NB_TRIG + NB_TQ + NB_TK + NB_TV + NB_TO, 256, 0, stream>>>(
        x, xb, tab, Wq, Wk, Wv, WqkvT, Wo, WobT);

    // 2) fused QKV projection: N=1152, 8-wave blocks; epi = RoPE-Q, RoPE-K, V^T
    k_gemm_r2<1><<<dim3((DM + 2 * DK) / 128, M / 128), 512, GEMM_LDS, stream>>>(
        xb, WqkvT, Qb, Kb, VbT, tab);

    // 3) attention (8-wave split-KV blocks, ring-2-pairs, counted vmcnt)
    k_attn<<<dim3(2 * NH * (SEQ / 128)), 512, 0, stream>>>(Qb, Kb, VbT, Ob);

    // 4) output projection -> d_out (8-wave blocks)
    k_gemm_r2<0><<<dim3(DM / 128, M / 128), 512, GEMM_LDS, stream>>>(
        Ob, WobT, out, nullptr, nullptr, nullptr);
}

// Round 16
// 97.754 us; speedup vs baseline: 1.0222x; 1.0000x over previous
//
#include <hip/hip_runtime.h>

#define DM 1024
#define NH 16
#define DK 64
#define SEQ 2048

typedef __attribute__((ext_vector_type(8))) __bf16 bf16x8;
typedef __attribute__((ext_vector_type(4))) float f32x4;
typedef __attribute__((ext_vector_type(16))) float f32x16;
typedef __attribute__((ext_vector_type(8))) unsigned short u16x8;
typedef __attribute__((ext_vector_type(4))) unsigned int u32x4;
typedef unsigned short u16;

#define MFMA(a, b, c) __builtin_amdgcn_mfma_f32_16x16x32_bf16(a, b, c, 0, 0, 0)
#define MFMA32(a, b, c) __builtin_amdgcn_mfma_f32_32x32x16_bf16(a, b, c, 0, 0, 0)

__device__ __forceinline__ u16 f2bf(float f) {
    unsigned u = __builtin_bit_cast(unsigned, f);
    u = (u + 0x7FFFu + ((u >> 16) & 1u)) >> 16;
    return (u16)u;
}

__device__ __forceinline__ bf16x8 ldb(const u16* p) {
    u16x8 v = *(const u16x8*)p;
    return __builtin_bit_cast(bf16x8, v);
}

__device__ __forceinline__ unsigned cvtpk(float a, float b) {
    unsigned r;
    asm("v_cvt_pk_bf16_f32 %0, %1, %2" : "=v"(r) : "v"(a), "v"(b));
    return r;
}

__device__ __forceinline__ void swap32(unsigned& a, unsigned& b) {
    asm volatile("v_permlane32_swap_b32 %0, %1" : "+v"(a), "+v"(b));
}

__device__ __forceinline__ float fexp2(float x) {
    return __builtin_amdgcn_exp2f(x);
}

// async global->LDS, 16B per lane, LDS dest = wave-uniform base + lane*16
__device__ __forceinline__ void gload16(const u16* g, u16* l) {
    __builtin_amdgcn_global_load_lds(
        (const __attribute__((address_space(1))) unsigned int*)g,
        (__attribute__((address_space(3))) unsigned int*)l, 16, 0, 0);
}

// ================= fused prep: cvt + trig table + 4 weight transposes =================
#define NB_CVT 4096
#define NB_TRIG 256
#define NB_TQ 1024
#define NB_TK 64
#define NB_TV 64
#define NB_TO 1024

__device__ __forceinline__ void do_transpose(const float* __restrict__ W,
                                             u16* __restrict__ WT, int ldW, int K,
                                             int bx, int by, float (*t)[33]) {
    int n0 = bx * 32, k0 = by * 32;
    int tx = threadIdx.x & 31, ty = threadIdx.x >> 5;
#pragma unroll
    for (int i = 0; i < 32; i += 8)
        t[ty + i][tx] = W[(long)(k0 + ty + i) * ldW + n0 + tx];
    __syncthreads();
#pragma unroll
    for (int i = 0; i < 32; i += 8)
        WT[(long)(n0 + ty + i) * K + k0 + tx] = f2bf(t[tx][ty + i]);
}

__global__ __launch_bounds__(256) void k_prep(const float* __restrict__ x,
                                              u16* __restrict__ xb,
                                              float2* __restrict__ tab,
                                              const float* __restrict__ Wq,
                                              const float* __restrict__ Wk,
                                              const float* __restrict__ Wv,
                                              u16* __restrict__ WqkvT,
                                              const float* __restrict__ Wo,
                                              u16* __restrict__ WobT) {
    __shared__ float tsh[32][33];
    int blk = blockIdx.x;
    if (blk < NB_CVT) {  // f32 -> bf16 convert, x4 vectorized
        int i = blk * 256 + threadIdx.x;
        float4 v = ((const float4*)x)[i];
        ushort4 o;
        o.x = f2bf(v.x); o.y = f2bf(v.y); o.z = f2bf(v.z); o.w = f2bf(v.w);
        ((ushort4*)xb)[i] = o;
        return;
    }
    blk -= NB_CVT;
    if (blk < NB_TRIG) {  // sincos table tab[s][i]
        int idx = blk * 256 + threadIdx.x;
        int i = idx & 31, s = idx >> 5;
        float theta = exp2f(-(float)i * 0.4152410118609203f);  // 10000^(-2i/64)
        float sn, cs;
        sincosf((float)s * theta, &sn, &cs);
        tab[idx] = make_float2(cs, sn);
        return;
    }
    blk -= NB_TRIG;
    if (blk < NB_TQ) { do_transpose(Wq, WqkvT, DM, DM, blk & 31, blk >> 5, tsh); return; }
    blk -= NB_TQ;
    if (blk < NB_TK) { do_transpose(Wk, WqkvT + (size_t)DM * DM, DK, DM, blk & 1, blk >> 1, tsh); return; }
    blk -= NB_TK;
    if (blk < NB_TV) { do_transpose(Wv, WqkvT + (size_t)(DM + DK) * DM, DK, DM, blk & 1, blk >> 1, tsh); return; }
    blk -= NB_TV;
    do_transpose(Wo, WobT, DM, DM, blk & 31, blk >> 5, tsh);
}

// ========== ring-2 GEMM, 8 waves (2 waves/SIMD), counted vmcnt ==========
// 128x128 tile, BK=64, 512 thr; wave (wr,wc) = (w>>2, w&3) owns 64x32 out.
// MODE 0: plain f32 C (N=1024). MODE 1: fused QKV epi (N=1152).
template <int MODE>
__global__ __launch_bounds__(512) void k_gemm_r2(const u16* __restrict__ A,
                                                 const u16* __restrict__ BT,
                                                 void* __restrict__ out0,
                                                 void* __restrict__ out1,
                                                 void* __restrict__ out2,
                                                 const float2* __restrict__ tab) {
    extern __shared__ __align__(16) u16 lds[];  // [2][A:8192] ++ [2][B:8192] (u16)
    const int NT = 16;                          // K=1024 / 64
    const int K = DM;
    int tid = threadIdx.x;
    int w = tid >> 6, lane = tid & 63, lg = lane >> 4, lr = lane & 15;
    int wr = w >> 2, wc = w & 3;
    long m0 = (long)blockIdx.y * 128, n0 = (long)blockIdx.x * 128;
    int lrow = lane >> 3, lcol = (lane & 7) * 8;

    f32x4 acc[4][2] = {};

#define GSTAGE(t)                                                                   \
    {                                                                               \
        u16* as_ = lds + ((t) & 1) * 8192;                                          \
        u16* bs_ = lds + 16384 + ((t) & 1) * 8192;                                  \
        int k0_ = (t) * 64;                                                         \
        _Pragma("unroll") for (int it = 0; it < 2; ++it) {                          \
            int row = w * 16 + it * 8;                                              \
            gload16(A + (m0 + row + lrow) * K + k0_ + lcol, as_ + row * 64);        \
            gload16(BT + (n0 + row + lrow) * K + k0_ + lcol, bs_ + row * 64);       \
        }                                                                           \
    }

    GSTAGE(0);
    GSTAGE(1);
    for (int t = 0; t < NT; ++t) {
        if (t + 1 < NT) {
            asm volatile("s_waitcnt vmcnt(4)" ::: "memory");  // K-step t landed (mine)
        } else {
            asm volatile("s_waitcnt vmcnt(0)" ::: "memory");
        }
        __builtin_amdgcn_s_barrier();  // K-step t landed (all waves)
        const u16* as = lds + (t & 1) * 8192;
        const u16* bs = lds + 16384 + (t & 1) * 8192;
#pragma unroll
        for (int kk = 0; kk < 64; kk += 32) {
            bf16x8 af[4], bf[2];
#pragma unroll
            for (int i = 0; i < 4; ++i)
                af[i] = ldb(as + (wr * 64 + i * 16 + lr) * 64 + kk + lg * 8);
#pragma unroll
            for (int j = 0; j < 2; ++j)
                bf[j] = ldb(bs + (wc * 32 + j * 16 + lr) * 64 + kk + lg * 8);
#pragma unroll
            for (int mi = 0; mi < 4; ++mi)
#pragma unroll
                for (int ni = 0; ni < 2; ++ni)
                    acc[mi][ni] = MFMA(af[mi], bf[ni], acc[mi][ni]);
        }
        __builtin_amdgcn_s_barrier();  // all waves done reading buf t&1
        if (t + 2 < NT) GSTAGE(t + 2);
    }
#undef GSTAGE

    if (MODE == 0) {  // plain f32 C, N=1024
        float* C = (float*)out0;
#pragma unroll
        for (int mi = 0; mi < 4; ++mi)
#pragma unroll
            for (int ni = 0; ni < 2; ++ni)
#pragma unroll
                for (int r = 0; r < 4; ++r) {
                    long row = m0 + wr * 64 + mi * 16 + lg * 4 + r;
                    long col = n0 + wc * 32 + ni * 16 + lr;
                    C[row * DM + col] = acc[mi][ni][r];
                }
    } else if (n0 < DM) {  // fused RoPE-Q (scaled by 0.125*log2e) -> bf16
        u16* Qb = (u16*)out0;
        const float SC = 0.18033688011112042f;
#pragma unroll
        for (int ni = 0; ni < 2; ++ni) {
            int col = (int)n0 + wc * 32 + ni * 16 + lr;
            int ii = (col & 63) >> 1;
#pragma unroll
            for (int mi = 0; mi < 4; ++mi) {
                long row0 = m0 + wr * 64 + mi * 16 + lg * 4;
#pragma unroll
                for (int r = 0; r < 4; ++r) {
                    int s = (int)(row0 + r) & (SEQ - 1);
                    float2 t = tab[s * 32 + ii];
                    float mine = acc[mi][ni][r];
                    float other = __shfl_xor(mine, 1);
                    float o = ((col & 1) ? (mine * t.x + other * t.y)
                                         : (mine * t.x - other * t.y)) * SC;
                    float oo = __shfl_xor(o, 1);
                    if (!(lr & 1))
                        *(unsigned*)(Qb + (row0 + r) * DM + col) = cvtpk(o, oo);
                }
            }
        }
    } else {  // KV block: cols 0-63 = K (RoPE, unscaled), cols 64-127 = V (transposed)
        u16* Kb = (u16*)out1;
        u16* VbT = (u16*)out2;
        if (wc < 2) {  // K half
#pragma unroll
            for (int ni = 0; ni < 2; ++ni) {
                int col = wc * 32 + ni * 16 + lr;  // 0..63
                int ii = col >> 1;
#pragma unroll
                for (int mi = 0; mi < 4; ++mi) {
                    long row0 = m0 + wr * 64 + mi * 16 + lg * 4;
#pragma unroll
                    for (int r = 0; r < 4; ++r) {
                        int s = (int)(row0 + r) & (SEQ - 1);
                        float2 t = tab[s * 32 + ii];
                        float mine = acc[mi][ni][r];
                        float other = __shfl_xor(mine, 1);
                        float o = (col & 1) ? (mine * t.x + other * t.y)
                                            : (mine * t.x - other * t.y);
                        float oo = __shfl_xor(o, 1);
                        if (!(lr & 1))
                            *(unsigned*)(Kb + (row0 + r) * DK + col) = cvtpk(o, oo);
                    }
                }
            }
        } else {  // V half -> VbT[b][d][s]
#pragma unroll
            for (int ni = 0; ni < 2; ++ni) {
                int d = (wc - 2) * 32 + ni * 16 + lr;  // 0..63
#pragma unroll
                for (int mi = 0; mi < 4; ++mi) {
                    long row0 = m0 + wr * 64 + mi * 16 + lg * 4;
#pragma unroll
                    for (int r = 0; r < 4; ++r) {
                        long row = row0 + r;
                        long bb = row >> 11;
                        int s = (int)row & (SEQ - 1);
                        VbT[bb * DK * SEQ + (long)d * SEQ + s] = f2bf(acc[mi][ni][r]);
                    }
                }
            }
        }
    }
}

// ==== attention: 8 waves (4 q-subs x 2 KV parities), TWO q-tiles per block ====
// Block u processes qt = 15-u then qt = u -> every block = 17 pair-steps (perfect
// balance, no idle tail). LDS: 2 pair-slots x [Ke|Ve|Ko|Vo] 8KB = 64KB; swizzle
// slot ^= (row&7); linear LDS dest + inverse-swizzled global source (rule #21).
__device__ __forceinline__ void stage_pair(u16* lds0, int pslot, int kv0,
                                           const u16* Kbase, const u16* Vbase,
                                           int w8, int lane) {
    int row = w8 * 8 + (lane >> 3), slot = lane & 7;
    int sw = (slot ^ (row & 7)) * 8;
    u16* base = lds0 + pslot * 16384 + w8 * 512;
    gload16(Kbase + (long)(kv0 + row) * DK + sw, base);
    gload16(Vbase + (long)row * SEQ + kv0 + sw, base + 4096);
    gload16(Kbase + (long)(kv0 + 64 + row) * DK + sw, base + 8192);
    gload16(Vbase + (long)row * SEQ + kv0 + 64 + sw, base + 12288);
}

__device__ __forceinline__ bf16x8 lds_frag(const u16* tile, int row, int slot) {
    return ldb(tile + row * 64 + ((slot ^ (row & 7)) * 8));
}

// Swapped QK^T: S^T[kv][q] = mfma(K, Q^T); crow(r,hi) = (r&3) + 8*(r>>2) + 4*hi.
// Swapped PV: O^T[d][q] = mfma(V^T, P^T). log2-domain softmax, deferred max (T13).
template <bool MASKED>
__device__ __forceinline__ void attn_tile(int kv0, int q, int lq, int hi,
                                          const u16* Kt, const u16* Vt,
                                          const bf16x8 qf[4],
                                          f32x16& o0, f32x16& o1,
                                          float& m, float& lsum) {
    f32x16 s0 = {}, s1 = {};
    __builtin_amdgcn_s_setprio(1);
#pragma unroll
    for (int ks = 0; ks < 4; ++ks) {
        s0 = MFMA32(lds_frag(Kt, lq, hi + 2 * ks), qf[ks], s0);
        s1 = MFMA32(lds_frag(Kt, lq + 32, hi + 2 * ks), qf[ks], s1);
    }
    __builtin_amdgcn_s_setprio(0);
    if (MASKED) {
#pragma unroll
        for (int r = 0; r < 16; ++r) {
            int crow = (r & 3) + 8 * (r >> 2) + 4 * hi;
            if (kv0 + crow > q) s0[r] = -3e38f;
            if (kv0 + 32 + crow > q) s1[r] = -3e38f;
        }
    }
    float t[8];
#pragma unroll
    for (int j = 0; j < 8; ++j)
        t[j] = fmaxf(fmaxf(s0[j], s0[j + 8]), fmaxf(s1[j], s1[j + 8]));
    float pmax = fmaxf(fmaxf(fmaxf(t[0], t[4]), fmaxf(t[1], t[5])),
                       fmaxf(fmaxf(t[2], t[6]), fmaxf(t[3], t[7])));
    pmax = fmaxf(pmax, __shfl_xor(pmax, 32));
    if (__any(pmax > m + 8.f)) {
        float mnew = fmaxf(m, pmax);
        float fac = fexp2(m - mnew);
        m = mnew;
        lsum *= fac;
        o0 *= fac;
        o1 *= fac;
    }
    float p0[16], p1[16];
#pragma unroll
    for (int r = 0; r < 16; ++r) {
        p0[r] = fexp2(s0[r] - m);
        p1[r] = fexp2(s1[r] - m);
    }
    float su[8];
#pragma unroll
    for (int j = 0; j < 8; ++j)
        su[j] = (p0[j] + p0[j + 8]) + (p1[j] + p1[j + 8]);
    float psum = ((su[0] + su[4]) + (su[1] + su[5])) + ((su[2] + su[6]) + (su[3] + su[7]));
    psum += __shfl_xor(psum, 32);
    lsum += psum;
    bf16x8 pa[4];
#pragma unroll
    for (int g = 0; g < 2; ++g) {
        unsigned a0 = cvtpk(p0[g * 8 + 0], p0[g * 8 + 1]);
        unsigned b0 = cvtpk(p0[g * 8 + 4], p0[g * 8 + 5]);
        swap32(a0, b0);
        unsigned a1 = cvtpk(p0[g * 8 + 2], p0[g * 8 + 3]);
        unsigned b1 = cvtpk(p0[g * 8 + 6], p0[g * 8 + 7]);
        swap32(a1, b1);
        u32x4 u = {a0, a1, b0, b1};
        pa[g] = __builtin_bit_cast(bf16x8, u);
    }
#pragma unroll
    for (int g = 0; g < 2; ++g) {
        unsigned a0 = cvtpk(p1[g * 8 + 0], p1[g * 8 + 1]);
        unsigned b0 = cvtpk(p1[g * 8 + 4], p1[g * 8 + 5]);
        swap32(a0, b0);
        unsigned a1 = cvtpk(p1[g * 8 + 2], p1[g * 8 + 3]);
        unsigned b1 = cvtpk(p1[g * 8 + 6], p1[g * 8 + 7]);
        swap32(a1, b1);
        u32x4 u = {a0, a1, b0, b1};
        pa[2 + g] = __builtin_bit_cast(bf16x8, u);
    }
    __builtin_amdgcn_s_setprio(1);
#pragma unroll
    for (int ks = 0; ks < 4; ++ks) {
        o0 = MFMA32(lds_frag(Vt, lq, hi + 2 * ks), pa[ks], o0);
        o1 = MFMA32(lds_frag(Vt, lq + 32, hi + 2 * ks), pa[ks], o1);
    }
    __builtin_amdgcn_s_setprio(0);
}

// grid: 256 blocks x 512 thr (8 waves). Per pair-step p: vmcnt(4) -> barrier ->
// compute tile 2p+par -> barrier -> stage pair p+2. After each phase: split-KV
// merge (odd parity publishes, even combines + stores), then next q-tile.
__global__ __launch_bounds__(512) void k_attn(const u16* __restrict__ Qb,
                                              const u16* __restrict__ Kb,
                                              const u16* __restrict__ VbT,
                                              u16* __restrict__ Ob) {
    __shared__ __align__(16) u16 lds[2][4][4096];  // [pair-slot][Ke|Ve|Ko|Vo] = 64KB
    u16* lds0 = &lds[0][0][0];
    int id = blockIdx.x;
    int h = id & 15, b = (id >> 4) & 1;
    int u5 = id >> 5;  // 0..7
    int tid = threadIdx.x;
    int w8 = tid >> 6, lane = tid & 63;
    int w = w8 & 3, par = w8 >> 2;  // q-sub, even/odd tile parity
    int lq = lane & 31, hi = lane >> 5;
    const u16* Kbase = Kb + (long)b * SEQ * DK;
    const u16* Vbase = VbT + (long)b * DK * SEQ;

    for (int ph = 0; ph < 2; ++ph) {
        int qt = ph == 0 ? 15 - u5 : u5;  // long phase first; total = 17 steps/block
        int qb0 = qt * 128;
        int q0w = qb0 + 32 * w;
        int q = q0w + lq;
        const u16* Qp = Qb + (long)(b * SEQ + q) * DM + h * DK + hi * 8;
        bf16x8 qf[4];
#pragma unroll
        for (int ks = 0; ks < 4; ++ks) qf[ks] = ldb(Qp + ks * 16);
        f32x16 o0 = {}, o1 = {};
        float m = -1e30f, lsum = 0.f;

        int npair = qt + 1;  // pairs of 64-kv tiles covering [0, qb0+128)
        stage_pair(lds0, 0, 0, Kbase, Vbase, w8, lane);
        if (npair > 1) stage_pair(lds0, 1, 128, Kbase, Vbase, w8, lane);
        for (int p = 0; p < npair; ++p) {
            if (p + 1 < npair) {
                asm volatile("s_waitcnt vmcnt(4)" ::: "memory");  // pair p landed (mine)
            } else {
                asm volatile("s_waitcnt vmcnt(0)" ::: "memory");
            }
            __builtin_amdgcn_s_barrier();  // pair p landed (all waves)
            int t = 2 * p + par;
            int kv0 = t * 64;
            const u16* Kt = lds0 + (p & 1) * 16384 + par * 8192;
            const u16* Vt = Kt + 4096;
            if (kv0 <= q0w + 31) {
                if (kv0 + 63 <= q0w)
                    attn_tile<false>(kv0, q, lq, hi, Kt, Vt, qf, o0, o1, m, lsum);
                else
                    attn_tile<true>(kv0, q, lq, hi, Kt, Vt, qf, o0, o1, m, lsum);
            }
            __builtin_amdgcn_s_barrier();  // all waves done reading pair p's slots
            if (p + 2 < npair)
                stage_pair(lds0, p & 1, (2 * p + 4) * 64, Kbase, Vbase, w8, lane);
        }

        // ---- split-KV merge: odd parity publishes (O, m, l); even combines ----
        __syncthreads();
        float* mrg = (float*)lds0;  // floats [0, 8704); Ot region at u16 20480
        if (par == 1) {
            float* dst = mrg + (w * 64 + lane) * 34;
#pragma unroll
            for (int r = 0; r < 16; ++r) { dst[r] = o0[r]; dst[16 + r] = o1[r]; }
            dst[32] = m;
            dst[33] = lsum;
        }
        __syncthreads();
        if (par == 0) {
            const float* src = mrg + (w * 64 + lane) * 34;
            float m_o = src[32], l_o = src[33];
            float mstar = fmaxf(m, m_o);
            float fe = fexp2(m - mstar), fo = fexp2(m_o - mstar);
            float linv = 1.f / (lsum * fe + l_o * fo);
#pragma unroll
            for (int r = 0; r < 16; ++r) {
                o0[r] = (o0[r] * fe + src[r] * fo) * linv;
                o1[r] = (o1[r] * fe + src[16 + r] * fo) * linv;
            }
            u16* Ot = lds0 + 20480 + w * 2304;  // 32x72 u16/wave (disjoint from mrg)
#pragma unroll
            for (int rq = 0; rq < 4; ++rq) {
                uint2 u0, u1;
                u0.x = cvtpk(o0[4 * rq + 0], o0[4 * rq + 1]);
                u0.y = cvtpk(o0[4 * rq + 2], o0[4 * rq + 3]);
                u1.x = cvtpk(o1[4 * rq + 0], o1[4 * rq + 1]);
                u1.y = cvtpk(o1[4 * rq + 2], o1[4 * rq + 3]);
                *(uint2*)&Ot[lq * 72 + rq * 8 + hi * 4] = u0;
                *(uint2*)&Ot[lq * 72 + 32 + rq * 8 + hi * 4] = u1;
            }
#pragma unroll
            for (int i2 = 0; i2 < 4; ++i2) {
                int c = i2 * 64 + lane;
                int row = c >> 3, col = (c & 7) * 8;
                u16x8 v = *(const u16x8*)&Ot[row * 72 + col];
                *(u16x8*)(Ob + (long)(b * SEQ + q0w + row) * DM + h * DK + col) = v;
            }
        }
        __syncthreads();  // phase done (merge scratch free) before next staging
    }
}

extern "C" void kernel_launch(void* const* d_in, const int* in_sizes, int n_in,
                              void* d_out, int out_size, void* d_ws, size_t ws_size,
                              hipStream_t stream) {
    const float* x = (const float*)d_in[0];
    const float* Wq = (const float*)d_in[1];
    const float* Wk = (const float*)d_in[2];
    const float* Wv = (const float*)d_in[3];
    const float* Wo = (const float*)d_in[4];
    float* out = (float*)d_out;

    const int M = 2 * SEQ;  // 4096 rows
    char* p = (char*)d_ws;
    u16* xb = (u16*)p;        p += (size_t)M * DM * 2;          // 8 MB
    u16* WqkvT = (u16*)p;     p += (size_t)(DM + 2 * DK) * DM * 2;  // 2.25 MB
    u16* WobT = (u16*)p;      p += (size_t)DM * DM * 2;         // 2 MB
    u16* Qb = (u16*)p;        p += (size_t)M * DM * 2;          // 8 MB
    u16* Kb = (u16*)p;        p += (size_t)M * DK * 2;          // 512 KB
    u16* VbT = (u16*)p;       p += (size_t)M * DK * 2;          // 512 KB
    u16* Ob = (u16*)p;        p += (size_t)M * DM * 2;          // 8 MB
    float2* tab = (float2*)p; p += (size_t)SEQ * 32 * 8;        // 512 KB

    const size_t GEMM_LDS = 2 * 2 * 8192 * sizeof(u16);  // 64 KB

    // 1) fused prep: cvt + trig + weight transposes (one launch)
    k_prep<<<NB_CVT + NB_TRIG + NB_TQ + NB_TK + NB_TV + NB_TO, 256, 0, stream>>>(
        x, xb, tab, Wq, Wk, Wv, WqkvT, Wo, WobT);

    // 2) fused QKV projection: N=1152, 8-wave blocks; epi = RoPE-Q, RoPE-K, V^T
    k_gemm_r2<1><<<dim3((DM + 2 * DK) / 128, M / 128), 512, GEMM_LDS, stream>>>(
        xb, WqkvT, Qb, Kb, VbT, tab);

    // 3) attention (256 equal-length blocks: q-tiles (15-u, u) per block)
    k_attn<<<dim3(2 * NH * 8), 512, 0, stream>>>(Qb, Kb, VbT, Ob);

    // 4) output projection -> d_out (8-wave blocks)
    k_gemm_r2<0><<<dim3(DM / 128, M / 128), 512, GEMM_LDS, stream>>>(
        Ob, WobT, out, nullptr, nullptr, nullptr);
}

// Round 17
// 85.571 us; speedup vs baseline: 1.1677x; 1.1424x over previous
//
#include <hip/hip_runtime.h>

#define DM 1024
#define NH 16
#define DK 64
#define SEQ 2048

typedef __attribute__((ext_vector_type(8))) __bf16 bf16x8;
typedef __attribute__((ext_vector_type(4))) float f32x4;
typedef __attribute__((ext_vector_type(16))) float f32x16;
typedef __attribute__((ext_vector_type(8))) unsigned short u16x8;
typedef __attribute__((ext_vector_type(4))) unsigned int u32x4;
typedef unsigned short u16;

#define MFMA(a, b, c) __builtin_amdgcn_mfma_f32_16x16x32_bf16(a, b, c, 0, 0, 0)
#define MFMA32(a, b, c) __builtin_amdgcn_mfma_f32_32x32x16_bf16(a, b, c, 0, 0, 0)

__device__ __forceinline__ u16 f2bf(float f) {
    unsigned u = __builtin_bit_cast(unsigned, f);
    u = (u + 0x7FFFu + ((u >> 16) & 1u)) >> 16;
    return (u16)u;
}

__device__ __forceinline__ bf16x8 ldb(const u16* p) {
    u16x8 v = *(const u16x8*)p;
    return __builtin_bit_cast(bf16x8, v);
}

__device__ __forceinline__ unsigned cvtpk(float a, float b) {
    unsigned r;
    asm("v_cvt_pk_bf16_f32 %0, %1, %2" : "=v"(r) : "v"(a), "v"(b));
    return r;
}

__device__ __forceinline__ void swap32(unsigned& a, unsigned& b) {
    asm volatile("v_permlane32_swap_b32 %0, %1" : "+v"(a), "+v"(b));
}

__device__ __forceinline__ float fexp2(float x) {
    return __builtin_amdgcn_exp2f(x);
}

// async global->LDS, 16B per lane, LDS dest = wave-uniform base + lane*16
__device__ __forceinline__ void gload16(const u16* g, u16* l) {
    __builtin_amdgcn_global_load_lds(
        (const __attribute__((address_space(1))) unsigned int*)g,
        (__attribute__((address_space(3))) unsigned int*)l, 16, 0, 0);
}

// ================= fused prep: cvt + trig table + 4 weight transposes =================
#define NB_CVT 4096
#define NB_TRIG 256
#define NB_TQ 1024
#define NB_TK 64
#define NB_TV 64
#define NB_TO 1024

__device__ __forceinline__ void do_transpose(const float* __restrict__ W,
                                             u16* __restrict__ WT, int ldW, int K,
                                             int bx, int by, float (*t)[33]) {
    int n0 = bx * 32, k0 = by * 32;
    int tx = threadIdx.x & 31, ty = threadIdx.x >> 5;
#pragma unroll
    for (int i = 0; i < 32; i += 8)
        t[ty + i][tx] = W[(long)(k0 + ty + i) * ldW + n0 + tx];
    __syncthreads();
#pragma unroll
    for (int i = 0; i < 32; i += 8)
        WT[(long)(n0 + ty + i) * K + k0 + tx] = f2bf(t[tx][ty + i]);
}

__global__ __launch_bounds__(256) void k_prep(const float* __restrict__ x,
                                              u16* __restrict__ xb,
                                              float2* __restrict__ tab,
                                              const float* __restrict__ Wq,
                                              const float* __restrict__ Wk,
                                              const float* __restrict__ Wv,
                                              u16* __restrict__ WqkvT,
                                              const float* __restrict__ Wo,
                                              u16* __restrict__ WobT) {
    __shared__ float tsh[32][33];
    int blk = blockIdx.x;
    if (blk < NB_CVT) {  // f32 -> bf16 convert, x4 vectorized
        int i = blk * 256 + threadIdx.x;
        float4 v = ((const float4*)x)[i];
        ushort4 o;
        o.x = f2bf(v.x); o.y = f2bf(v.y); o.z = f2bf(v.z); o.w = f2bf(v.w);
        ((ushort4*)xb)[i] = o;
        return;
    }
    blk -= NB_CVT;
    if (blk < NB_TRIG) {  // sincos table tab[s][i]
        int idx = blk * 256 + threadIdx.x;
        int i = idx & 31, s = idx >> 5;
        float theta = exp2f(-(float)i * 0.4152410118609203f);  // 10000^(-2i/64)
        float sn, cs;
        sincosf((float)s * theta, &sn, &cs);
        tab[idx] = make_float2(cs, sn);
        return;
    }
    blk -= NB_TRIG;
    if (blk < NB_TQ) { do_transpose(Wq, WqkvT, DM, DM, blk & 31, blk >> 5, tsh); return; }
    blk -= NB_TQ;
    if (blk < NB_TK) { do_transpose(Wk, WqkvT + (size_t)DM * DM, DK, DM, blk & 1, blk >> 1, tsh); return; }
    blk -= NB_TK;
    if (blk < NB_TV) { do_transpose(Wv, WqkvT + (size_t)(DM + DK) * DM, DK, DM, blk & 1, blk >> 1, tsh); return; }
    blk -= NB_TV;
    do_transpose(Wo, WobT, DM, DM, blk & 31, blk >> 5, tsh);
}

// ========== ring-2 GEMM, 8 waves, counted vmcnt, T2 XOR-swizzled LDS ==========
// 128x128 tile, BK=64, 512 thr; wave (wr,wc) = (w>>2, w&3) owns 64x32 out.
// LDS [row][8 x 16B-slot]: LDS[row][s] holds global col-slot s^(row&7) (rule #21:
// linear LDS dest + pre-swizzled GLOBAL source; reads apply the same involution).
// MODE 0: plain f32 C (N=1024). MODE 1: fused QKV epi (N=1152).
template <int MODE>
__global__ __launch_bounds__(512) void k_gemm_r2(const u16* __restrict__ A,
                                                 const u16* __restrict__ BT,
                                                 void* __restrict__ out0,
                                                 void* __restrict__ out1,
                                                 void* __restrict__ out2,
                                                 const float2* __restrict__ tab) {
    extern __shared__ __align__(16) u16 lds[];  // [2][A:8192] ++ [2][B:8192] (u16)
    const int NT = 16;                          // K=1024 / 64
    const int K = DM;
    int tid = threadIdx.x;
    int w = tid >> 6, lane = tid & 63, lg = lane >> 4, lr = lane & 15;
    int wr = w >> 2, wc = w & 3;
    long m0 = (long)blockIdx.y * 128, n0 = (long)blockIdx.x * 128;
    int lrow = lane >> 3;                       // 0..7 within 8-row stripe
    int lcsw = (((lane & 7) ^ lrow) * 8);       // pre-swizzled source col (u16)

    f32x4 acc[4][2] = {};

#define GSTAGE(t)                                                                   \
    {                                                                               \
        u16* as_ = lds + ((t) & 1) * 8192;                                          \
        u16* bs_ = lds + 16384 + ((t) & 1) * 8192;                                  \
        int k0_ = (t) * 64;                                                         \
        _Pragma("unroll") for (int it = 0; it < 2; ++it) {                          \
            int row = w * 16 + it * 8;                                              \
            gload16(A + (m0 + row + lrow) * K + k0_ + lcsw, as_ + row * 64);        \
            gload16(BT + (n0 + row + lrow) * K + k0_ + lcsw, bs_ + row * 64);       \
        }                                                                           \
    }

    GSTAGE(0);
    GSTAGE(1);
    for (int t = 0; t < NT; ++t) {
        if (t + 1 < NT) {
            asm volatile("s_waitcnt vmcnt(4)" ::: "memory");  // K-step t landed (mine)
        } else {
            asm volatile("s_waitcnt vmcnt(0)" ::: "memory");
        }
        __builtin_amdgcn_s_barrier();  // K-step t landed (all waves)
        const u16* as = lds + (t & 1) * 8192;
        const u16* bs = lds + 16384 + (t & 1) * 8192;
#pragma unroll
        for (int kk = 0; kk < 64; kk += 32) {
            int sbase = lg + (kk >> 3);  // logical 16B-slot of this fragment
            int ssw = (sbase ^ (lr & 7)) * 8;
            bf16x8 af[4], bf[2];
#pragma unroll
            for (int i = 0; i < 4; ++i)
                af[i] = ldb(as + (wr * 64 + i * 16 + lr) * 64 + ssw);
#pragma unroll
            for (int j = 0; j < 2; ++j)
                bf[j] = ldb(bs + (wc * 32 + j * 16 + lr) * 64 + ssw);
#pragma unroll
            for (int mi = 0; mi < 4; ++mi)
#pragma unroll
                for (int ni = 0; ni < 2; ++ni)
                    acc[mi][ni] = MFMA(af[mi], bf[ni], acc[mi][ni]);
        }
        __builtin_amdgcn_s_barrier();  // all waves done reading buf t&1
        if (t + 2 < NT) GSTAGE(t + 2);
    }
#undef GSTAGE

    if (MODE == 0) {  // plain f32 C, N=1024
        float* C = (float*)out0;
#pragma unroll
        for (int mi = 0; mi < 4; ++mi)
#pragma unroll
            for (int ni = 0; ni < 2; ++ni)
#pragma unroll
                for (int r = 0; r < 4; ++r) {
                    long row = m0 + wr * 64 + mi * 16 + lg * 4 + r;
                    long col = n0 + wc * 32 + ni * 16 + lr;
                    C[row * DM + col] = acc[mi][ni][r];
                }
    } else if (n0 < DM) {  // fused RoPE-Q (scaled by 0.125*log2e) -> bf16
        u16* Qb = (u16*)out0;
        const float SC = 0.18033688011112042f;
#pragma unroll
        for (int ni = 0; ni < 2; ++ni) {
            int col = (int)n0 + wc * 32 + ni * 16 + lr;
            int ii = (col & 63) >> 1;
#pragma unroll
            for (int mi = 0; mi < 4; ++mi) {
                long row0 = m0 + wr * 64 + mi * 16 + lg * 4;
#pragma unroll
                for (int r = 0; r < 4; ++r) {
                    int s = (int)(row0 + r) & (SEQ - 1);
                    float2 t = tab[s * 32 + ii];
                    float mine = acc[mi][ni][r];
                    float other = __shfl_xor(mine, 1);
                    float o = ((col & 1) ? (mine * t.x + other * t.y)
                                         : (mine * t.x - other * t.y)) * SC;
                    float oo = __shfl_xor(o, 1);
                    if (!(lr & 1))
                        *(unsigned*)(Qb + (row0 + r) * DM + col) = cvtpk(o, oo);
                }
            }
        }
    } else {  // KV block: cols 0-63 = K (RoPE, unscaled), cols 64-127 = V (transposed)
        u16* Kb = (u16*)out1;
        u16* VbT = (u16*)out2;
        if (wc < 2) {  // K half
#pragma unroll
            for (int ni = 0; ni < 2; ++ni) {
                int col = wc * 32 + ni * 16 + lr;  // 0..63
                int ii = col >> 1;
#pragma unroll
                for (int mi = 0; mi < 4; ++mi) {
                    long row0 = m0 + wr * 64 + mi * 16 + lg * 4;
#pragma unroll
                    for (int r = 0; r < 4; ++r) {
                        int s = (int)(row0 + r) & (SEQ - 1);
                        float2 t = tab[s * 32 + ii];
                        float mine = acc[mi][ni][r];
                        float other = __shfl_xor(mine, 1);
                        float o = (col & 1) ? (mine * t.x + other * t.y)
                                            : (mine * t.x - other * t.y);
                        float oo = __shfl_xor(o, 1);
                        if (!(lr & 1))
                            *(unsigned*)(Kb + (row0 + r) * DK + col) = cvtpk(o, oo);
                    }
                }
            }
        } else {  // V half -> VbT[b][d][s]
#pragma unroll
            for (int ni = 0; ni < 2; ++ni) {
                int d = (wc - 2) * 32 + ni * 16 + lr;  // 0..63
#pragma unroll
                for (int mi = 0; mi < 4; ++mi) {
                    long row0 = m0 + wr * 64 + mi * 16 + lg * 4;
#pragma unroll
                    for (int r = 0; r < 4; ++r) {
                        long row = row0 + r;
                        long bb = row >> 11;
                        int s = (int)row & (SEQ - 1);
                        VbT[bb * DK * SEQ + (long)d * SEQ + s] = f2bf(acc[mi][ni][r]);
                    }
                }
            }
        }
    }
}

// ==== attention: 8 waves (4 q-subs x 2 KV parities), TWO q-tiles per block ====
// Block u processes qt = 15-u then qt = u -> every block = 17 pair-steps.
__device__ __forceinline__ void stage_pair(u16* lds0, int pslot, int kv0,
                                           const u16* Kbase, const u16* Vbase,
                                           int w8, int lane) {
    int row = w8 * 8 + (lane >> 3), slot = lane & 7;
    int sw = (slot ^ (row & 7)) * 8;
    u16* base = lds0 + pslot * 16384 + w8 * 512;
    gload16(Kbase + (long)(kv0 + row) * DK + sw, base);
    gload16(Vbase + (long)row * SEQ + kv0 + sw, base + 4096);
    gload16(Kbase + (long)(kv0 + 64 + row) * DK + sw, base + 8192);
    gload16(Vbase + (long)row * SEQ + kv0 + 64 + sw, base + 12288);
}

__device__ __forceinline__ bf16x8 lds_frag(const u16* tile, int row, int slot) {
    return ldb(tile + row * 64 + ((slot ^ (row & 7)) * 8));
}

// Swapped QK^T: S^T[kv][q] = mfma(K, Q^T); crow(r,hi) = (r&3) + 8*(r>>2) + 4*hi.
// Swapped PV: O^T[d][q] = mfma(V^T, P^T). log2-domain softmax, deferred max (T13).
template <bool MASKED>
__device__ __forceinline__ void attn_tile(int kv0, int q, int lq, int hi,
                                          const u16* Kt, const u16* Vt,
                                          const bf16x8 qf[4],
                                          f32x16& o0, f32x16& o1,
                                          float& m, float& lsum) {
    f32x16 s0 = {}, s1 = {};
    __builtin_amdgcn_s_setprio(1);
#pragma unroll
    for (int ks = 0; ks < 4; ++ks) {
        s0 = MFMA32(lds_frag(Kt, lq, hi + 2 * ks), qf[ks], s0);
        s1 = MFMA32(lds_frag(Kt, lq + 32, hi + 2 * ks), qf[ks], s1);
    }
    __builtin_amdgcn_s_setprio(0);
    if (MASKED) {
#pragma unroll
        for (int r = 0; r < 16; ++r) {
            int crow = (r & 3) + 8 * (r >> 2) + 4 * hi;
            if (kv0 + crow > q) s0[r] = -3e38f;
            if (kv0 + 32 + crow > q) s1[r] = -3e38f;
        }
    }
    float t[8];
#pragma unroll
    for (int j = 0; j < 8; ++j)
        t[j] = fmaxf(fmaxf(s0[j], s0[j + 8]), fmaxf(s1[j], s1[j + 8]));
    float pmax = fmaxf(fmaxf(fmaxf(t[0], t[4]), fmaxf(t[1], t[5])),
                       fmaxf(fmaxf(t[2], t[6]), fmaxf(t[3], t[7])));
    pmax = fmaxf(pmax, __shfl_xor(pmax, 32));
    if (__any(pmax > m + 8.f)) {
        float mnew = fmaxf(m, pmax);
        float fac = fexp2(m - mnew);
        m = mnew;
        lsum *= fac;
        o0 *= fac;
        o1 *= fac;
    }
    float p0[16], p1[16];
#pragma unroll
    for (int r = 0; r < 16; ++r) {
        p0[r] = fexp2(s0[r] - m);
        p1[r] = fexp2(s1[r] - m);
    }
    float su[8];
#pragma unroll
    for (int j = 0; j < 8; ++j)
        su[j] = (p0[j] + p0[j + 8]) + (p1[j] + p1[j + 8]);
    float psum = ((su[0] + su[4]) + (su[1] + su[5])) + ((su[2] + su[6]) + (su[3] + su[7]));
    psum += __shfl_xor(psum, 32);
    lsum += psum;
    bf16x8 pa[4];
#pragma unroll
    for (int g = 0; g < 2; ++g) {
        unsigned a0 = cvtpk(p0[g * 8 + 0], p0[g * 8 + 1]);
        unsigned b0 = cvtpk(p0[g * 8 + 4], p0[g * 8 + 5]);
        swap32(a0, b0);
        unsigned a1 = cvtpk(p0[g * 8 + 2], p0[g * 8 + 3]);
        unsigned b1 = cvtpk(p0[g * 8 + 6], p0[g * 8 + 7]);
        swap32(a1, b1);
        u32x4 u = {a0, a1, b0, b1};
        pa[g] = __builtin_bit_cast(bf16x8, u);
    }
#pragma unroll
    for (int g = 0; g < 2; ++g) {
        unsigned a0 = cvtpk(p1[g * 8 + 0], p1[g * 8 + 1]);
        unsigned b0 = cvtpk(p1[g * 8 + 4], p1[g * 8 + 5]);
        swap32(a0, b0);
        unsigned a1 = cvtpk(p1[g * 8 + 2], p1[g * 8 + 3]);
        unsigned b1 = cvtpk(p1[g * 8 + 6], p1[g * 8 + 7]);
        swap32(a1, b1);
        u32x4 u = {a0, a1, b0, b1};
        pa[2 + g] = __builtin_bit_cast(bf16x8, u);
    }
    __builtin_amdgcn_s_setprio(1);
#pragma unroll
    for (int ks = 0; ks < 4; ++ks) {
        o0 = MFMA32(lds_frag(Vt, lq, hi + 2 * ks), pa[ks], o0);
        o1 = MFMA32(lds_frag(Vt, lq + 32, hi + 2 * ks), pa[ks], o1);
    }
    __builtin_amdgcn_s_setprio(0);
}

// grid: 256 blocks x 512 thr (8 waves). Per pair-step p: vmcnt(4) -> barrier ->
// compute tile 2p+par -> barrier -> stage pair p+2. After each phase: split-KV
// merge (odd parity publishes, even combines + stores), then next q-tile.
__global__ __launch_bounds__(512) void k_attn(const u16* __restrict__ Qb,
                                              const u16* __restrict__ Kb,
                                              const u16* __restrict__ VbT,
                                              u16* __restrict__ Ob) {
    __shared__ __align__(16) u16 lds[2][4][4096];  // [pair-slot][Ke|Ve|Ko|Vo] = 64KB
    u16* lds0 = &lds[0][0][0];
    int id = blockIdx.x;
    int h = id & 15, b = (id >> 4) & 1;
    int u5 = id >> 5;  // 0..7
    int tid = threadIdx.x;
    int w8 = tid >> 6, lane = tid & 63;
    int w = w8 & 3, par = w8 >> 2;  // q-sub, even/odd tile parity
    int lq = lane & 31, hi = lane >> 5;
    const u16* Kbase = Kb + (long)b * SEQ * DK;
    const u16* Vbase = VbT + (long)b * DK * SEQ;

    for (int ph = 0; ph < 2; ++ph) {
        int qt = ph == 0 ? 15 - u5 : u5;  // long phase first; total = 17 steps/block
        int qb0 = qt * 128;
        int q0w = qb0 + 32 * w;
        int q = q0w + lq;
        const u16* Qp = Qb + (long)(b * SEQ + q) * DM + h * DK + hi * 8;
        bf16x8 qf[4];
#pragma unroll
        for (int ks = 0; ks < 4; ++ks) qf[ks] = ldb(Qp + ks * 16);
        f32x16 o0 = {}, o1 = {};
        float m = -1e30f, lsum = 0.f;

        int npair = qt + 1;  // pairs of 64-kv tiles covering [0, qb0+128)
        stage_pair(lds0, 0, 0, Kbase, Vbase, w8, lane);
        if (npair > 1) stage_pair(lds0, 1, 128, Kbase, Vbase, w8, lane);
        for (int p = 0; p < npair; ++p) {
            if (p + 1 < npair) {
                asm volatile("s_waitcnt vmcnt(4)" ::: "memory");  // pair p landed (mine)
            } else {
                asm volatile("s_waitcnt vmcnt(0)" ::: "memory");
            }
            __builtin_amdgcn_s_barrier();  // pair p landed (all waves)
            int t = 2 * p + par;
            int kv0 = t * 64;
            const u16* Kt = lds0 + (p & 1) * 16384 + par * 8192;
            const u16* Vt = Kt + 4096;
            if (kv0 <= q0w + 31) {
                if (kv0 + 63 <= q0w)
                    attn_tile<false>(kv0, q, lq, hi, Kt, Vt, qf, o0, o1, m, lsum);
                else
                    attn_tile<true>(kv0, q, lq, hi, Kt, Vt, qf, o0, o1, m, lsum);
            }
            __builtin_amdgcn_s_barrier();  // all waves done reading pair p's slots
            if (p + 2 < npair)
                stage_pair(lds0, p & 1, (2 * p + 4) * 64, Kbase, Vbase, w8, lane);
        }

        // ---- split-KV merge: odd parity publishes (O, m, l); even combines ----
        __syncthreads();
        float* mrg = (float*)lds0;  // floats [0, 8704); Ot region at u16 20480
        if (par == 1) {
            float* dst = mrg + (w * 64 + lane) * 34;
#pragma unroll
            for (int r = 0; r < 16; ++r) { dst[r] = o0[r]; dst[16 + r] = o1[r]; }
            dst[32] = m;
            dst[33] = lsum;
        }
        __syncthreads();
        if (par == 0) {
            const float* src = mrg + (w * 64 + lane) * 34;
            float m_o = src[32], l_o = src[33];
            float mstar = fmaxf(m, m_o);
            float fe = fexp2(m - mstar), fo = fexp2(m_o - mstar);
            float linv = 1.f / (lsum * fe + l_o * fo);
#pragma unroll
            for (int r = 0; r < 16; ++r) {
                o0[r] = (o0[r] * fe + src[r] * fo) * linv;
                o1[r] = (o1[r] * fe + src[16 + r] * fo) * linv;
            }
            u16* Ot = lds0 + 20480 + w * 2304;  // 32x72 u16/wave (disjoint from mrg)
#pragma unroll
            for (int rq = 0; rq < 4; ++rq) {
                uint2 u0, u1;
                u0.x = cvtpk(o0[4 * rq + 0], o0[4 * rq + 1]);
                u0.y = cvtpk(o0[4 * rq + 2], o0[4 * rq + 3]);
                u1.x = cvtpk(o1[4 * rq + 0], o1[4 * rq + 1]);
                u1.y = cvtpk(o1[4 * rq + 2], o1[4 * rq + 3]);
                *(uint2*)&Ot[lq * 72 + rq * 8 + hi * 4] = u0;
                *(uint2*)&Ot[lq * 72 + 32 + rq * 8 + hi * 4] = u1;
            }
#pragma unroll
            for (int i2 = 0; i2 < 4; ++i2) {
                int c = i2 * 64 + lane;
                int row = c >> 3, col = (c & 7) * 8;
                u16x8 v = *(const u16x8*)&Ot[row * 72 + col];
                *(u16x8*)(Ob + (long)(b * SEQ + q0w + row) * DM + h * DK + col) = v;
            }
        }
        __syncthreads();  // phase done (merge scratch free) before next staging
    }
}

extern "C" void kernel_launch(void* const* d_in, const int* in_sizes, int n_in,
                              void* d_out, int out_size, void* d_ws, size_t ws_size,
                              hipStream_t stream) {
    const float* x = (const float*)d_in[0];
    const float* Wq = (const float*)d_in[1];
    const float* Wk = (const float*)d_in[2];
    const float* Wv = (const float*)d_in[3];
    const float* Wo = (const float*)d_in[4];
    float* out = (float*)d_out;

    const int M = 2 * SEQ;  // 4096 rows
    char* p = (char*)d_ws;
    u16* xb = (u16*)p;        p += (size_t)M * DM * 2;          // 8 MB
    u16* WqkvT = (u16*)p;     p += (size_t)(DM + 2 * DK) * DM * 2;  // 2.25 MB
    u16* WobT = (u16*)p;      p += (size_t)DM * DM * 2;         // 2 MB
    u16* Qb = (u16*)p;        p += (size_t)M * DM * 2;          // 8 MB
    u16* Kb = (u16*)p;        p += (size_t)M * DK * 2;          // 512 KB
    u16* VbT = (u16*)p;       p += (size_t)M * DK * 2;          // 512 KB
    u16* Ob = (u16*)p;        p += (size_t)M * DM * 2;          // 8 MB
    float2* tab = (float2*)p; p += (size_t)SEQ * 32 * 8;        // 512 KB

    const size_t GEMM_LDS = 2 * 2 * 8192 * sizeof(u16);  // 64 KB

    // 1) fused prep: cvt + trig + weight transposes (one launch)
    k_prep<<<NB_CVT + NB_TRIG + NB_TQ + NB_TK + NB_TV + NB_TO, 256, 0, stream>>>(
        x, xb, tab, Wq, Wk, Wv, WqkvT, Wo, WobT);

    // 2) fused QKV projection: N=1152, 8-wave blocks; epi = RoPE-Q, RoPE-K, V^T
    k_gemm_r2<1><<<dim3((DM + 2 * DK) / 128, M / 128), 512, GEMM_LDS, stream>>>(
        xb, WqkvT, Qb, Kb, VbT, tab);

    // 3) attention (256 equal-length blocks: q-tiles (15-u, u) per block)
    k_attn<<<dim3(2 * NH * 8), 512, 0, stream>>>(Qb, Kb, VbT, Ob);

    // 4) output projection -> d_out (8-wave blocks, swizzled LDS)
    k_gemm_r2<0><<<dim3(DM / 128, M / 128), 512, GEMM_LDS, stream>>>(
        Ob, WobT, out, nullptr, nullptr, nullptr);
}